// Round 1
// baseline (499.480 us; speedup 1.0000x reference)
//
#include <hip/hip_runtime.h>
#include <math.h>

#define BB 64
#define LL 512
#define RR 512
#define DD 512
#define FC 100
#define HH 60
#define BD (BB*DD)

// ---------------- batched attention GEMM: att[b][l][r] = (lv[l,b,:]·rv[r,b,:]) * lm * rm ----------
__global__ __launch_bounds__(256) void gemm_att(const float* __restrict__ lv,
                                                const float* __restrict__ rv,
                                                const int* __restrict__ llen,
                                                const int* __restrict__ rlen,
                                                float* __restrict__ att) {
  __shared__ float As[16][68];
  __shared__ float Bs[16][68];
  const int b  = blockIdx.z;
  const int l0 = blockIdx.y * 64;
  const int r0 = blockIdx.x * 64;
  const int t  = threadIdx.x;
  const int tx = t & 15, ty = t >> 4;
  const int li = t >> 2, lk = (t & 3) * 4;
  const float* Ab = lv + (size_t)(l0 + li) * BD + b * DD + lk;
  const float* Bb = rv + (size_t)(r0 + li) * BD + b * DD + lk;
  float acc[4][4] = {{0.f}};
  for (int k0 = 0; k0 < DD; k0 += 16) {
    float4 a4 = *(const float4*)(Ab + k0);
    float4 b4 = *(const float4*)(Bb + k0);
    As[lk+0][li] = a4.x; As[lk+1][li] = a4.y; As[lk+2][li] = a4.z; As[lk+3][li] = a4.w;
    Bs[lk+0][li] = b4.x; Bs[lk+1][li] = b4.y; Bs[lk+2][li] = b4.z; Bs[lk+3][li] = b4.w;
    __syncthreads();
#pragma unroll
    for (int k = 0; k < 16; ++k) {
      float4 av = *(const float4*)&As[k][ty*4];
      float4 bv = *(const float4*)&Bs[k][tx*4];
      float a[4] = {av.x, av.y, av.z, av.w};
      float bq[4] = {bv.x, bv.y, bv.z, bv.w};
#pragma unroll
      for (int i = 0; i < 4; ++i)
#pragma unroll
        for (int j = 0; j < 4; ++j) acc[i][j] += a[i] * bq[j];
    }
    __syncthreads();
  }
  const int ll_ = llen[b], rl_ = rlen[b];
#pragma unroll
  for (int i = 0; i < 4; ++i) {
    int l = l0 + ty*4 + i;
    float lm = (l < ll_) ? 1.f : 0.f;
    float* orow = att + ((size_t)b * LL + l) * RR + r0 + tx*4;
#pragma unroll
    for (int j = 0; j < 4; ++j) {
      int r = r0 + tx*4 + j;
      float m = (r < rl_) ? lm : 0.f;
      orow[j] = acc[i][j] * m;
    }
  }
}

// ---------------- wave reduce helpers ----------------
__device__ __forceinline__ float wmaxf(float v) {
#pragma unroll
  for (int m = 32; m; m >>= 1) v = fmaxf(v, __shfl_xor(v, m, 64));
  return v;
}
__device__ __forceinline__ float wsumf(float v) {
#pragma unroll
  for (int m = 32; m; m >>= 1) v += __shfl_xor(v, m, 64);
  return v;
}

// ---------------- l-side stats: softmax over r (rows of att), per (b,l) ----------------
__global__ __launch_bounds__(256) void stats_rows(const float* __restrict__ att,
    const int* __restrict__ llen, const int* __restrict__ rlen,
    float* __restrict__ w_out, float* __restrict__ an_out, int* __restrict__ idx_out) {
  const int lane = threadIdx.x & 63;
  const int row  = blockIdx.x * 4 + (threadIdx.x >> 6);  // row = b*512 + l
  const int b = row >> 9, l = row & 511;
  const int rl_ = rlen[b], ll_ = llen[b];
  const float* base = att + (size_t)row * RR;
  float s[8];
#pragma unroll
  for (int j = 0; j < 8; ++j) {
    int r = lane + 64*j;
    float v = base[r];
    s[j] = (r < rl_) ? v : v - 10.f;   // masked entries have v==0 -> -10
  }
  float M = -1e30f;
#pragma unroll
  for (int j = 0; j < 8; ++j) M = fmaxf(M, s[j]);
  M = wmaxf(M);
  float e[8]; float z0 = 0.f, zv = 0.f;
  float bv = -1e30f; int bi = 0;
#pragma unroll
  for (int j = 0; j < 8; ++j) {
    int r = lane + 64*j;
    float ej = __expf(s[j] - M);
    z0 += ej;
    bool valid = (r < rl_);
    float evj = valid ? ej : 0.f;
    e[j] = evj;
    zv += evj;
    if (valid && evj > bv) { bv = evj; bi = r; }   // per-lane first max (r ascending)
  }
  z0 = wsumf(z0); zv = wsumf(zv);
  const float S = zv / z0;
  const float inv = 1.f / (S + 1e-13f);
  const float c = inv / z0;     // final att_l value = ev * c
  float q2 = 0.f;
#pragma unroll
  for (int j = 0; j < 8; ++j) { float q = e[j] * c; q2 += q * q; }
  q2 = wsumf(q2);
#pragma unroll
  for (int m = 32; m; m >>= 1) {
    float ov = __shfl_xor(bv, m, 64);
    int   oi = __shfl_xor(bi, m, 64);
    if (ov > bv || (ov == bv && oi < bi)) { bv = ov; bi = oi; }
  }
  if (lane == 0) {
    float rlf = (float)rl_;
    float sumq = S * inv;
    float mean = sumq / rlf;
    float var  = q2 / rlf - mean * mean;
    float wv   = var / fmaxf(mean, 0.001f);
    float qmax = bv * c;
    float an   = qmax / fmaxf(qmax, 0.001f);
    w_out[row]  = wv;
    an_out[row] = an;
    idx_out[row] = (l < ll_) ? bi : 0;
  }
}

// ---------------- r-side stats: softmax over l (columns of att), per (b,r) ----------------
__global__ __launch_bounds__(256) void stats_cols(const float* __restrict__ att,
    const int* __restrict__ llen, const int* __restrict__ rlen,
    float* __restrict__ w_out, float* __restrict__ an_out, int* __restrict__ idx_out) {
  __shared__ float mM[4][64], mZ[4][64], mZv[4][64], mQ[4][64], mB[4][64];
  __shared__ int   mI[4][64];
  const int b  = blockIdx.x >> 3;
  const int r0 = (blockIdx.x & 7) * 64;
  const int t  = threadIdx.x;
  const int cl = t & 63;
  const int part = t >> 6;
  const int col = r0 + cl;
  const int ll_ = llen[b], rl_ = rlen[b];
  const float* base = att + ((size_t)b * LL) * RR + col;
  float M = -1e30f, Z = 0.f, Zv = 0.f, Q = 0.f, bS = -1e30f;
  int bI = 0;
  const int l0 = part * 128;
  for (int li = 0; li < 128; ++li) {
    int l = l0 + li;
    float v = base[(size_t)l * RR];
    bool lmv = (l < ll_);
    float s = lmv ? v : v - 10.f;
    if (s > M) {
      float sc = __expf(M - s);
      Z *= sc; Zv *= sc; Q *= sc * sc;
      M = s;
    }
    float ej = __expf(s - M);
    Z += ej;
    if (lmv) {
      Zv += ej; Q += ej * ej;
      if (s > bS) { bS = s; bI = l; }   // first max, l ascending
    }
  }
  mM[part][cl] = M; mZ[part][cl] = Z; mZv[part][cl] = Zv;
  mQ[part][cl] = Q; mB[part][cl] = bS; mI[part][cl] = bI;
  __syncthreads();
  if (t < 64) {
    float M0 = mM[0][t], Z0 = mZ[0][t], Zv0 = mZv[0][t], Q0 = mQ[0][t], bS0 = mB[0][t];
    int bI0 = mI[0][t];
#pragma unroll
    for (int p = 1; p < 4; ++p) {
      float M1 = mM[p][t], Z1 = mZ[p][t], Zv1 = mZv[p][t], Q1 = mQ[p][t], bS1 = mB[p][t];
      int bI1 = mI[p][t];
      float Mn = fmaxf(M0, M1);
      float c0 = __expf(M0 - Mn), c1 = __expf(M1 - Mn);
      Z0  = Z0 * c0 + Z1 * c1;
      Zv0 = Zv0 * c0 + Zv1 * c1;
      Q0  = Q0 * c0 * c0 + Q1 * c1 * c1;
      M0 = Mn;
      if (bS1 > bS0) { bS0 = bS1; bI0 = bI1; }    // parts in ascending-l order, strict >
    }
    const float S = Zv0 / Z0;
    const float inv = 1.f / (S + 1e-13f);
    float llf = (float)ll_;
    float sumq = S * inv;
    float mean = sumq / llf;
    float sumq2 = Q0 / (Z0 * Z0) * inv * inv;
    float var = sumq2 / llf - mean * mean;
    float wv = var / fmaxf(mean, 0.001f);
    float qmax = __expf(bS0 - M0) / Z0 * inv;
    float an = qmax / fmaxf(qmax, 0.001f);
    int c_ = r0 + t;
    w_out[b * RR + c_]  = wv;
    an_out[b * RR + c_] = an;
    idx_out[b * RR + c_] = (c_ < rl_) ? bI0 : 0;
  }
}

// ---------------- transpose Wconv [100][512] -> WT [512][100] ----------------
__global__ void transpose_w(const float* __restrict__ Wconv, float* __restrict__ WT) {
  int i = blockIdx.x * 256 + threadIdx.x;
  if (i < FC * DD) {
    int f = i / DD, d = i % DD;
    WT[d * FC + f] = Wconv[i];
  }
}

// ---------------- conv (per-position linear D->100) + relu + masked maxpool ----------------
__global__ __launch_bounds__(256) void conv_pool(const float* __restrict__ lv,
    const float* __restrict__ rv,
    const float* __restrict__ lwv, const float* __restrict__ lan, const int* __restrict__ lidx,
    const float* __restrict__ rwv, const float* __restrict__ ran, const int* __restrict__ ridx,
    const int* __restrict__ llen, const int* __restrict__ rlen,
    const float* __restrict__ WT, const float* __restrict__ bconv,
    float* __restrict__ feat) {
  __shared__ float wt_s[64][100];
  __shared__ float sc[16][64];
  __shared__ float pw[16], pan[16];
  __shared__ int   pidx[16], pval[16];
  __shared__ float pool[8][128];
  const int side = blockIdx.z;
  const int b = blockIdx.y;
  const int s0 = blockIdx.x * 16;
  const int t = threadIdx.x;
  const float* x; const float* y; const float* wb; const float* ab; const int* ib; int plen;
  if (side == 0) { x = lv; y = rv; wb = lwv; ab = lan; ib = lidx; plen = llen[b]; }
  else           { x = rv; y = lv; wb = rwv; ab = ran; ib = ridx; plen = rlen[b]; }
  if (t < 16) {
    int pos = s0 + t;
    pw[t]   = wb[b * 512 + pos];
    pan[t]  = ab[b * 512 + pos];
    pidx[t] = ib[b * 512 + pos];
    pval[t] = (pos < plen) ? 1 : 0;
  }
  __syncthreads();
  const int f4 = (t & 31) * 4;
  const int l2 = (t >> 5) * 2;
  const int lp = t >> 4;
  const int dq = (t & 15) * 4;
  float acc[2][4] = {{0.f}};
  for (int d0 = 0; d0 < DD; d0 += 64) {
    for (int j = t; j < 64 * FC; j += 256) ((float*)wt_s)[j] = WT[d0 * FC + j];
    {
      float4 res;
      if (pval[lp]) {
        int pos = s0 + lp;
        const float4 xv = *(const float4*)(x + (size_t)pos * BD + b * DD + d0 + dq);
        const float4 yv = *(const float4*)(y + (size_t)pidx[lp] * BD + b * DD + d0 + dq);
        float wv = pw[lp], a_ = pan[lp];
        res.x = wv * fabsf(xv.x - a_ * yv.x);
        res.y = wv * fabsf(xv.y - a_ * yv.y);
        res.z = wv * fabsf(xv.z - a_ * yv.z);
        res.w = wv * fabsf(xv.w - a_ * yv.w);
      } else {
        res = make_float4(0.f, 0.f, 0.f, 0.f);
      }
      *(float4*)&sc[lp][dq] = res;
    }
    __syncthreads();
    if (f4 < FC) {
      for (int d = 0; d < 64; ++d) {
        float a0 = sc[l2][d], a1 = sc[l2 + 1][d];
        const float4 wv4 = *(const float4*)&wt_s[d][f4];
        acc[0][0] += a0 * wv4.x; acc[0][1] += a0 * wv4.y;
        acc[0][2] += a0 * wv4.z; acc[0][3] += a0 * wv4.w;
        acc[1][0] += a1 * wv4.x; acc[1][1] += a1 * wv4.y;
        acc[1][2] += a1 * wv4.z; acc[1][3] += a1 * wv4.w;
      }
    }
    __syncthreads();
  }
  float hm[4];
#pragma unroll
  for (int q = 0; q < 4; ++q) {
    float v = -1e30f;
    if (f4 + q < FC) {
      float bc = bconv[f4 + q];
      if (pval[l2])     v = fmaxf(v, fmaxf(acc[0][q] + bc, 0.f));
      if (pval[l2 + 1]) v = fmaxf(v, fmaxf(acc[1][q] + bc, 0.f));
    }
    hm[q] = v;
  }
  *(float4*)&pool[t >> 5][f4] = make_float4(hm[0], hm[1], hm[2], hm[3]);
  __syncthreads();
  if (t < 32) {
#pragma unroll
    for (int q = 0; q < 4; ++q) {
      int f = t * 4 + q;
      if (f < FC) {
        float v = -1e30f;
#pragma unroll
        for (int g = 0; g < 8; ++g) v = fmaxf(v, pool[g][f]);
        if (v > -1e29f) atomicMax((int*)&feat[b * 200 + side * FC + f], __float_as_int(v));
      }
    }
  }
}

// ---------------- final dense [B,200] x [200,60] + relu ----------------
__global__ void dense_out(const float* __restrict__ feat, const float* __restrict__ Wd,
                          const float* __restrict__ bd, float* __restrict__ out) {
  int b = blockIdx.x, h = threadIdx.x;
  if (h < HH) {
    float s = bd[h];
    const float* fb = feat + b * 200;
    const float* wr = Wd + h * 200;
    for (int k = 0; k < 200; ++k) s += fb[k] * wr[k];
    out[b * HH + h] = fmaxf(s, 0.f);
  }
}

extern "C" void kernel_launch(void* const* d_in, const int* in_sizes, int n_in,
                              void* d_out, int out_size, void* d_ws, size_t ws_size,
                              hipStream_t stream) {
  (void)in_sizes; (void)n_in; (void)out_size; (void)ws_size;
  const int*   llen  = (const int*)d_in[0];
  const float* lv    = (const float*)d_in[1];
  const int*   rlen  = (const int*)d_in[2];
  const float* rv    = (const float*)d_in[3];
  const float* Wconv = (const float*)d_in[4];
  const float* bconv = (const float*)d_in[5];
  const float* Wd    = (const float*)d_in[6];
  const float* bd    = (const float*)d_in[7];
  float* out = (float*)d_out;
  char* ws = (char*)d_ws;
  size_t off = 0;
  float* att = (float*)(ws + off); off += (size_t)BB * LL * RR * 4;  // 67,108,864 B
  float* WT  = (float*)(ws + off); off += (size_t)DD * FC * 4;
  float* lwv = (float*)(ws + off); off += (size_t)BB * LL * 4;
  float* lan = (float*)(ws + off); off += (size_t)BB * LL * 4;
  int*   lidx= (int*)  (ws + off); off += (size_t)BB * LL * 4;
  float* rwv = (float*)(ws + off); off += (size_t)BB * RR * 4;
  float* ran = (float*)(ws + off); off += (size_t)BB * RR * 4;
  int*   ridx= (int*)  (ws + off); off += (size_t)BB * RR * 4;
  float* feat= (float*)(ws + off); off += (size_t)BB * 200 * 4;

  hipMemsetAsync(feat, 0, BB * 200 * 4, stream);
  transpose_w<<<(FC * DD + 255) / 256, 256, 0, stream>>>(Wconv, WT);
  gemm_att<<<dim3(RR / 64, LL / 64, BB), 256, 0, stream>>>(lv, rv, llen, rlen, att);
  stats_rows<<<BB * LL / 4, 256, 0, stream>>>(att, llen, rlen, lwv, lan, lidx);
  stats_cols<<<BB * 8, 256, 0, stream>>>(att, llen, rlen, rwv, ran, ridx);
  conv_pool<<<dim3(LL / 16, BB, 2), 256, 0, stream>>>(lv, rv, lwv, lan, lidx,
                                                      rwv, ran, ridx, llen, rlen,
                                                      WT, bconv, feat);
  dense_out<<<BB, 64, 0, stream>>>(feat, Wd, bd, out);
}

// Round 2
// 296.668 us; speedup vs baseline: 1.6836x; 1.6836x over previous
//
#include <hip/hip_runtime.h>
#include <math.h>

#define BB 64
#define LL 512
#define RR 512
#define DD 512
#define FC 100
#define HH 60
#define BD (BB*DD)

typedef __attribute__((ext_vector_type(8))) short bf16x8;
typedef __attribute__((ext_vector_type(4))) float f32x4;

__device__ __forceinline__ unsigned short bf16rne(float x) {
  unsigned u = __float_as_uint(x);
  return (unsigned short)((u + 0x7fffu + ((u >> 16) & 1u)) >> 16);
}
__device__ __forceinline__ float bf16tof(unsigned short h) {
  return __uint_as_float((unsigned)h << 16);
}

// ---------------- batched attention GEMM via bf16 hi/lo split MFMA ----------------
// att[b][l][r] = (lv[l,b,:]·rv[r,b,:]) * lmask * rmask
__global__ __launch_bounds__(256) void gemm_att(const float* __restrict__ lv,
                                                const float* __restrict__ rv,
                                                const int* __restrict__ llen,
                                                const int* __restrict__ rlen,
                                                float* __restrict__ att) {
  __shared__ unsigned short Ah[128][40];
  __shared__ unsigned short Al[128][40];
  __shared__ unsigned short Bh[128][40];
  __shared__ unsigned short Bl[128][40];

  // XCD-aware bijective swizzle: 1024 blocks, 8 XCDs -> each XCD gets 128
  // contiguous work-ids = 8 full batches (A/B panels L2-resident per XCD).
  const int bid = blockIdx.x;
  const int wid = (bid & 7) * 128 + (bid >> 3);
  const int b  = wid >> 4;
  const int l0 = ((wid >> 2) & 3) * 128;
  const int r0 = (wid & 3) * 128;

  const int t = threadIdx.x;
  const int row16 = t >> 3;        // 0..31
  const int kq = (t & 7) * 4;      // 0,4,..28

  const float* Abase = lv + (size_t)(l0 + row16) * BD + b * DD + kq;
  const float* Bbase = rv + (size_t)(r0 + row16) * BD + b * DD + kq;

  float4 pa[4], pb[4];
#pragma unroll
  for (int p = 0; p < 4; ++p) {
    pa[p] = *(const float4*)(Abase + (size_t)p * 32 * BD);
    pb[p] = *(const float4*)(Bbase + (size_t)p * 32 * BD);
  }

  const int lane = t & 63;
  const int wv = t >> 6;
  const int wr = (wv >> 1) * 64;
  const int wc = (wv & 1) * 64;
  const int fr = lane & 15;
  const int kh = lane >> 4;        // 0..3

  f32x4 acc[4][4];
#pragma unroll
  for (int i = 0; i < 4; ++i)
#pragma unroll
    for (int j = 0; j < 4; ++j) acc[i][j] = (f32x4){0.f, 0.f, 0.f, 0.f};

  for (int it = 0; it < 16; ++it) {
    __syncthreads();   // previous iteration's ds_reads complete
#pragma unroll
    for (int p = 0; p < 4; ++p) {
      int rr = p * 32 + row16;
      ushort4 h, l;
      h.x = bf16rne(pa[p].x); l.x = bf16rne(pa[p].x - bf16tof(h.x));
      h.y = bf16rne(pa[p].y); l.y = bf16rne(pa[p].y - bf16tof(h.y));
      h.z = bf16rne(pa[p].z); l.z = bf16rne(pa[p].z - bf16tof(h.z));
      h.w = bf16rne(pa[p].w); l.w = bf16rne(pa[p].w - bf16tof(h.w));
      *(ushort4*)&Ah[rr][kq] = h;
      *(ushort4*)&Al[rr][kq] = l;
      h.x = bf16rne(pb[p].x); l.x = bf16rne(pb[p].x - bf16tof(h.x));
      h.y = bf16rne(pb[p].y); l.y = bf16rne(pb[p].y - bf16tof(h.y));
      h.z = bf16rne(pb[p].z); l.z = bf16rne(pb[p].z - bf16tof(h.z));
      h.w = bf16rne(pb[p].w); l.w = bf16rne(pb[p].w - bf16tof(h.w));
      *(ushort4*)&Bh[rr][kq] = h;
      *(ushort4*)&Bl[rr][kq] = l;
    }
    if (it < 15) {
      const float* An = Abase + (it + 1) * 32;
      const float* Bn = Bbase + (it + 1) * 32;
#pragma unroll
      for (int p = 0; p < 4; ++p) {
        pa[p] = *(const float4*)(An + (size_t)p * 32 * BD);
        pb[p] = *(const float4*)(Bn + (size_t)p * 32 * BD);
      }
    }
    __syncthreads();   // LDS writes visible

    bf16x8 ah[4], al[4], bh[4], bl[4];
#pragma unroll
    for (int i = 0; i < 4; ++i) {
      ah[i] = *(const bf16x8*)&Ah[wr + i * 16 + fr][kh * 8];
      al[i] = *(const bf16x8*)&Al[wr + i * 16 + fr][kh * 8];
      bh[i] = *(const bf16x8*)&Bh[wc + i * 16 + fr][kh * 8];
      bl[i] = *(const bf16x8*)&Bl[wc + i * 16 + fr][kh * 8];
    }
#pragma unroll
    for (int i = 0; i < 4; ++i)
#pragma unroll
      for (int j = 0; j < 4; ++j) {
        acc[i][j] = __builtin_amdgcn_mfma_f32_16x16x32_bf16(ah[i], bh[j], acc[i][j], 0, 0, 0);
        acc[i][j] = __builtin_amdgcn_mfma_f32_16x16x32_bf16(ah[i], bl[j], acc[i][j], 0, 0, 0);
        acc[i][j] = __builtin_amdgcn_mfma_f32_16x16x32_bf16(al[i], bh[j], acc[i][j], 0, 0, 0);
      }
  }

  const int ll_ = llen[b], rl_ = rlen[b];
#pragma unroll
  for (int i = 0; i < 4; ++i) {
#pragma unroll
    for (int q = 0; q < 4; ++q) {
      int l = l0 + wr + i * 16 + kh * 4 + q;
      float lm = (l < ll_) ? 1.f : 0.f;
      float* orow = att + ((size_t)b * LL + l) * RR + r0 + wc;
#pragma unroll
      for (int j = 0; j < 4; ++j) {
        int r = r0 + wc + j * 16 + fr;
        float m = (r < rl_) ? lm : 0.f;
        orow[j * 16 + fr] = acc[i][j][q] * m;
      }
    }
  }
}

// ---------------- wave reduce helpers ----------------
__device__ __forceinline__ float wmaxf(float v) {
#pragma unroll
  for (int m = 32; m; m >>= 1) v = fmaxf(v, __shfl_xor(v, m, 64));
  return v;
}
__device__ __forceinline__ float wsumf(float v) {
#pragma unroll
  for (int m = 32; m; m >>= 1) v += __shfl_xor(v, m, 64);
  return v;
}

// ---------------- l-side stats: softmax over r (rows of att), per (b,l) ----------------
__global__ __launch_bounds__(256) void stats_rows(const float* __restrict__ att,
    const int* __restrict__ llen, const int* __restrict__ rlen,
    float* __restrict__ w_out, float* __restrict__ an_out, int* __restrict__ idx_out) {
  const int lane = threadIdx.x & 63;
  const int row  = blockIdx.x * 4 + (threadIdx.x >> 6);  // row = b*512 + l
  const int b = row >> 9, l = row & 511;
  const int rl_ = rlen[b], ll_ = llen[b];
  const float* base = att + (size_t)row * RR;
  float s[8];
#pragma unroll
  for (int j = 0; j < 8; ++j) {
    int r = lane + 64*j;
    float v = base[r];
    s[j] = (r < rl_) ? v : v - 10.f;   // masked entries have v==0 -> -10
  }
  float M = -1e30f;
#pragma unroll
  for (int j = 0; j < 8; ++j) M = fmaxf(M, s[j]);
  M = wmaxf(M);
  float e[8]; float z0 = 0.f, zv = 0.f;
  float bv = -1e30f; int bi = 0;
#pragma unroll
  for (int j = 0; j < 8; ++j) {
    int r = lane + 64*j;
    float ej = __expf(s[j] - M);
    z0 += ej;
    bool valid = (r < rl_);
    float evj = valid ? ej : 0.f;
    e[j] = evj;
    zv += evj;
    if (valid && evj > bv) { bv = evj; bi = r; }   // per-lane first max (r ascending)
  }
  z0 = wsumf(z0); zv = wsumf(zv);
  const float S = zv / z0;
  const float inv = 1.f / (S + 1e-13f);
  const float c = inv / z0;     // final att_l value = ev * c
  float q2 = 0.f;
#pragma unroll
  for (int j = 0; j < 8; ++j) { float q = e[j] * c; q2 += q * q; }
  q2 = wsumf(q2);
#pragma unroll
  for (int m = 32; m; m >>= 1) {
    float ov = __shfl_xor(bv, m, 64);
    int   oi = __shfl_xor(bi, m, 64);
    if (ov > bv || (ov == bv && oi < bi)) { bv = ov; bi = oi; }
  }
  if (lane == 0) {
    float rlf = (float)rl_;
    float sumq = S * inv;
    float mean = sumq / rlf;
    float var  = q2 / rlf - mean * mean;
    float wv   = var / fmaxf(mean, 0.001f);
    float qmax = bv * c;
    float an   = qmax / fmaxf(qmax, 0.001f);
    w_out[row]  = wv;
    an_out[row] = an;
    idx_out[row] = (l < ll_) ? bi : 0;
  }
}

// ---------------- r-side stats: softmax over l (columns of att), per (b,r) ----------------
__global__ __launch_bounds__(256) void stats_cols(const float* __restrict__ att,
    const int* __restrict__ llen, const int* __restrict__ rlen,
    float* __restrict__ w_out, float* __restrict__ an_out, int* __restrict__ idx_out) {
  __shared__ float mM[4][64], mZ[4][64], mZv[4][64], mQ[4][64], mB[4][64];
  __shared__ int   mI[4][64];
  const int b  = blockIdx.x >> 3;
  const int r0 = (blockIdx.x & 7) * 64;
  const int t  = threadIdx.x;
  const int cl = t & 63;
  const int part = t >> 6;
  const int col = r0 + cl;
  const int ll_ = llen[b], rl_ = rlen[b];
  const float* base = att + ((size_t)b * LL) * RR + col;
  float M = -1e30f, Z = 0.f, Zv = 0.f, Q = 0.f, bS = -1e30f;
  int bI = 0;
  const int l0 = part * 128;
  for (int li = 0; li < 128; ++li) {
    int l = l0 + li;
    float v = base[(size_t)l * RR];
    bool lmv = (l < ll_);
    float s = lmv ? v : v - 10.f;
    if (s > M) {
      float sc = __expf(M - s);
      Z *= sc; Zv *= sc; Q *= sc * sc;
      M = s;
    }
    float ej = __expf(s - M);
    Z += ej;
    if (lmv) {
      Zv += ej; Q += ej * ej;
      if (s > bS) { bS = s; bI = l; }   // first max, l ascending
    }
  }
  mM[part][cl] = M; mZ[part][cl] = Z; mZv[part][cl] = Zv;
  mQ[part][cl] = Q; mB[part][cl] = bS; mI[part][cl] = bI;
  __syncthreads();
  if (t < 64) {
    float M0 = mM[0][t], Z0 = mZ[0][t], Zv0 = mZv[0][t], Q0 = mQ[0][t], bS0 = mB[0][t];
    int bI0 = mI[0][t];
#pragma unroll
    for (int p = 1; p < 4; ++p) {
      float M1 = mM[p][t], Z1 = mZ[p][t], Zv1 = mZv[p][t], Q1 = mQ[p][t], bS1 = mB[p][t];
      int bI1 = mI[p][t];
      float Mn = fmaxf(M0, M1);
      float c0 = __expf(M0 - Mn), c1 = __expf(M1 - Mn);
      Z0  = Z0 * c0 + Z1 * c1;
      Zv0 = Zv0 * c0 + Zv1 * c1;
      Q0  = Q0 * c0 * c0 + Q1 * c1 * c1;
      M0 = Mn;
      if (bS1 > bS0) { bS0 = bS1; bI0 = bI1; }    // parts in ascending-l order, strict >
    }
    const float S = Zv0 / Z0;
    const float inv = 1.f / (S + 1e-13f);
    float llf = (float)ll_;
    float sumq = S * inv;
    float mean = sumq / llf;
    float sumq2 = Q0 / (Z0 * Z0) * inv * inv;
    float var = sumq2 / llf - mean * mean;
    float wv = var / fmaxf(mean, 0.001f);
    float qmax = __expf(bS0 - M0) / Z0 * inv;
    float an = qmax / fmaxf(qmax, 0.001f);
    int c_ = r0 + t;
    w_out[b * RR + c_]  = wv;
    an_out[b * RR + c_] = an;
    idx_out[b * RR + c_] = (c_ < rl_) ? bI0 : 0;
  }
}

// ---------------- transpose Wconv [100][512] -> WT [512][100] ----------------
__global__ void transpose_w(const float* __restrict__ Wconv, float* __restrict__ WT) {
  int i = blockIdx.x * 256 + threadIdx.x;
  if (i < FC * DD) {
    int f = i / DD, d = i % DD;
    WT[d * FC + f] = Wconv[i];
  }
}

// ---------------- conv (per-position linear D->100) + relu + masked maxpool ----------------
__global__ __launch_bounds__(256) void conv_pool(const float* __restrict__ lv,
    const float* __restrict__ rv,
    const float* __restrict__ lwv, const float* __restrict__ lan, const int* __restrict__ lidx,
    const float* __restrict__ rwv, const float* __restrict__ ran, const int* __restrict__ ridx,
    const int* __restrict__ llen, const int* __restrict__ rlen,
    const float* __restrict__ WT, const float* __restrict__ bconv,
    float* __restrict__ feat) {
  __shared__ float wt_s[64][100];
  __shared__ float sc[16][64];
  __shared__ float pw[16], pan[16];
  __shared__ int   pidx[16], pval[16];
  __shared__ float pool[8][128];
  const int side = blockIdx.z;
  const int b = blockIdx.y;
  const int s0 = blockIdx.x * 16;
  const int t = threadIdx.x;
  const float* x; const float* y; const float* wb; const float* ab; const int* ib; int plen;
  if (side == 0) { x = lv; y = rv; wb = lwv; ab = lan; ib = lidx; plen = llen[b]; }
  else           { x = rv; y = lv; wb = rwv; ab = ran; ib = ridx; plen = rlen[b]; }
  if (t < 16) {
    int pos = s0 + t;
    pw[t]   = wb[b * 512 + pos];
    pan[t]  = ab[b * 512 + pos];
    pidx[t] = ib[b * 512 + pos];
    pval[t] = (pos < plen) ? 1 : 0;
  }
  __syncthreads();
  const int f4 = (t & 31) * 4;
  const int l2 = (t >> 5) * 2;
  const int lp = t >> 4;
  const int dq = (t & 15) * 4;
  float acc[2][4] = {{0.f}};
  for (int d0 = 0; d0 < DD; d0 += 64) {
    for (int j = t; j < 64 * FC; j += 256) ((float*)wt_s)[j] = WT[d0 * FC + j];
    {
      float4 res;
      if (pval[lp]) {
        int pos = s0 + lp;
        const float4 xv = *(const float4*)(x + (size_t)pos * BD + b * DD + d0 + dq);
        const float4 yv = *(const float4*)(y + (size_t)pidx[lp] * BD + b * DD + d0 + dq);
        float wv = pw[lp], a_ = pan[lp];
        res.x = wv * fabsf(xv.x - a_ * yv.x);
        res.y = wv * fabsf(xv.y - a_ * yv.y);
        res.z = wv * fabsf(xv.z - a_ * yv.z);
        res.w = wv * fabsf(xv.w - a_ * yv.w);
      } else {
        res = make_float4(0.f, 0.f, 0.f, 0.f);
      }
      *(float4*)&sc[lp][dq] = res;
    }
    __syncthreads();
    if (f4 < FC) {
      for (int d = 0; d < 64; ++d) {
        float a0 = sc[l2][d], a1 = sc[l2 + 1][d];
        const float4 wv4 = *(const float4*)&wt_s[d][f4];
        acc[0][0] += a0 * wv4.x; acc[0][1] += a0 * wv4.y;
        acc[0][2] += a0 * wv4.z; acc[0][3] += a0 * wv4.w;
        acc[1][0] += a1 * wv4.x; acc[1][1] += a1 * wv4.y;
        acc[1][2] += a1 * wv4.z; acc[1][3] += a1 * wv4.w;
      }
    }
    __syncthreads();
  }
  float hm[4];
#pragma unroll
  for (int q = 0; q < 4; ++q) {
    float v = -1e30f;
    if (f4 + q < FC) {
      float bc = bconv[f4 + q];
      if (pval[l2])     v = fmaxf(v, fmaxf(acc[0][q] + bc, 0.f));
      if (pval[l2 + 1]) v = fmaxf(v, fmaxf(acc[1][q] + bc, 0.f));
    }
    hm[q] = v;
  }
  *(float4*)&pool[t >> 5][f4] = make_float4(hm[0], hm[1], hm[2], hm[3]);
  __syncthreads();
  if (t < 32) {
#pragma unroll
    for (int q = 0; q < 4; ++q) {
      int f = t * 4 + q;
      if (f < FC) {
        float v = -1e30f;
#pragma unroll
        for (int g = 0; g < 8; ++g) v = fmaxf(v, pool[g][f]);
        if (v > -1e29f) atomicMax((int*)&feat[b * 200 + side * FC + f], __float_as_int(v));
      }
    }
  }
}

// ---------------- final dense [B,200] x [200,60] + relu ----------------
__global__ void dense_out(const float* __restrict__ feat, const float* __restrict__ Wd,
                          const float* __restrict__ bd, float* __restrict__ out) {
  int b = blockIdx.x, h = threadIdx.x;
  if (h < HH) {
    float s = bd[h];
    const float* fb = feat + b * 200;
    const float* wr = Wd + h * 200;
    for (int k = 0; k < 200; ++k) s += fb[k] * wr[k];
    out[b * HH + h] = fmaxf(s, 0.f);
  }
}

extern "C" void kernel_launch(void* const* d_in, const int* in_sizes, int n_in,
                              void* d_out, int out_size, void* d_ws, size_t ws_size,
                              hipStream_t stream) {
  (void)in_sizes; (void)n_in; (void)out_size; (void)ws_size;
  const int*   llen  = (const int*)d_in[0];
  const float* lv    = (const float*)d_in[1];
  const int*   rlen  = (const int*)d_in[2];
  const float* rv    = (const float*)d_in[3];
  const float* Wconv = (const float*)d_in[4];
  const float* bconv = (const float*)d_in[5];
  const float* Wd    = (const float*)d_in[6];
  const float* bd    = (const float*)d_in[7];
  float* out = (float*)d_out;
  char* ws = (char*)d_ws;
  size_t off = 0;
  float* att = (float*)(ws + off); off += (size_t)BB * LL * RR * 4;  // 67,108,864 B
  float* WT  = (float*)(ws + off); off += (size_t)DD * FC * 4;
  float* lwv = (float*)(ws + off); off += (size_t)BB * LL * 4;
  float* lan = (float*)(ws + off); off += (size_t)BB * LL * 4;
  int*   lidx= (int*)  (ws + off); off += (size_t)BB * LL * 4;
  float* rwv = (float*)(ws + off); off += (size_t)BB * RR * 4;
  float* ran = (float*)(ws + off); off += (size_t)BB * RR * 4;
  int*   ridx= (int*)  (ws + off); off += (size_t)BB * RR * 4;
  float* feat= (float*)(ws + off); off += (size_t)BB * 200 * 4;

  hipMemsetAsync(feat, 0, BB * 200 * 4, stream);
  transpose_w<<<(FC * DD + 255) / 256, 256, 0, stream>>>(Wconv, WT);
  gemm_att<<<dim3(1024), 256, 0, stream>>>(lv, rv, llen, rlen, att);
  stats_rows<<<BB * LL / 4, 256, 0, stream>>>(att, llen, rlen, lwv, lan, lidx);
  stats_cols<<<BB * 8, 256, 0, stream>>>(att, llen, rlen, rwv, ran, ridx);
  conv_pool<<<dim3(LL / 16, BB, 2), 256, 0, stream>>>(lv, rv, lwv, lan, lidx,
                                                      rwv, ran, ridx, llen, rlen,
                                                      WT, bconv, feat);
  dense_out<<<BB, 64, 0, stream>>>(feat, Wd, bd, out);
}

// Round 3
// 182.189 us; speedup vs baseline: 2.7415x; 1.6284x over previous
//
#include <hip/hip_runtime.h>
#include <math.h>

#define BB 64
#define LL 512
#define RR 512
#define DD 512
#define FC 100
#define FP 112
#define HH 60
#define BD (BB*DD)

typedef __attribute__((ext_vector_type(8))) short bf16x8;
typedef __attribute__((ext_vector_type(4))) float f32x4;

__device__ __forceinline__ unsigned short bf16rne(float x) {
  unsigned u = __float_as_uint(x);
  return (unsigned short)((u + 0x7fffu + ((u >> 16) & 1u)) >> 16);
}
__device__ __forceinline__ float bf16tof(unsigned short h) {
  return __uint_as_float((unsigned)h << 16);
}

// ---------------- batched attention GEMM via bf16 hi/lo split MFMA ----------------
__global__ __launch_bounds__(256) void gemm_att(const float* __restrict__ lv,
                                                const float* __restrict__ rv,
                                                const int* __restrict__ llen,
                                                const int* __restrict__ rlen,
                                                float* __restrict__ att) {
  __shared__ unsigned short Ah[128][40];
  __shared__ unsigned short Al[128][40];
  __shared__ unsigned short Bh[128][40];
  __shared__ unsigned short Bl[128][40];

  const int bid = blockIdx.x;
  const int wid = (bid & 7) * 128 + (bid >> 3);
  const int b  = wid >> 4;
  const int l0 = ((wid >> 2) & 3) * 128;
  const int r0 = (wid & 3) * 128;

  const int t = threadIdx.x;
  const int row16 = t >> 3;        // 0..31
  const int kq = (t & 7) * 4;      // 0,4,..28

  const float* Abase = lv + (size_t)(l0 + row16) * BD + b * DD + kq;
  const float* Bbase = rv + (size_t)(r0 + row16) * BD + b * DD + kq;

  float4 pa[4], pb[4];
#pragma unroll
  for (int p = 0; p < 4; ++p) {
    pa[p] = *(const float4*)(Abase + (size_t)p * 32 * BD);
    pb[p] = *(const float4*)(Bbase + (size_t)p * 32 * BD);
  }

  const int lane = t & 63;
  const int wv = t >> 6;
  const int wr = (wv >> 1) * 64;
  const int wc = (wv & 1) * 64;
  const int fr = lane & 15;
  const int kh = lane >> 4;        // 0..3

  f32x4 acc[4][4];
#pragma unroll
  for (int i = 0; i < 4; ++i)
#pragma unroll
    for (int j = 0; j < 4; ++j) acc[i][j] = (f32x4){0.f, 0.f, 0.f, 0.f};

  for (int it = 0; it < 16; ++it) {
    __syncthreads();
#pragma unroll
    for (int p = 0; p < 4; ++p) {
      int rr = p * 32 + row16;
      ushort4 h, l;
      h.x = bf16rne(pa[p].x); l.x = bf16rne(pa[p].x - bf16tof(h.x));
      h.y = bf16rne(pa[p].y); l.y = bf16rne(pa[p].y - bf16tof(h.y));
      h.z = bf16rne(pa[p].z); l.z = bf16rne(pa[p].z - bf16tof(h.z));
      h.w = bf16rne(pa[p].w); l.w = bf16rne(pa[p].w - bf16tof(h.w));
      *(ushort4*)&Ah[rr][kq] = h;
      *(ushort4*)&Al[rr][kq] = l;
      h.x = bf16rne(pb[p].x); l.x = bf16rne(pb[p].x - bf16tof(h.x));
      h.y = bf16rne(pb[p].y); l.y = bf16rne(pb[p].y - bf16tof(h.y));
      h.z = bf16rne(pb[p].z); l.z = bf16rne(pb[p].z - bf16tof(h.z));
      h.w = bf16rne(pb[p].w); l.w = bf16rne(pb[p].w - bf16tof(h.w));
      *(ushort4*)&Bh[rr][kq] = h;
      *(ushort4*)&Bl[rr][kq] = l;
    }
    if (it < 15) {
      const float* An = Abase + (it + 1) * 32;
      const float* Bn = Bbase + (it + 1) * 32;
#pragma unroll
      for (int p = 0; p < 4; ++p) {
        pa[p] = *(const float4*)(An + (size_t)p * 32 * BD);
        pb[p] = *(const float4*)(Bn + (size_t)p * 32 * BD);
      }
    }
    __syncthreads();

    bf16x8 ah[4], al[4], bh[4], bl[4];
#pragma unroll
    for (int i = 0; i < 4; ++i) {
      ah[i] = *(const bf16x8*)&Ah[wr + i * 16 + fr][kh * 8];
      al[i] = *(const bf16x8*)&Al[wr + i * 16 + fr][kh * 8];
      bh[i] = *(const bf16x8*)&Bh[wc + i * 16 + fr][kh * 8];
      bl[i] = *(const bf16x8*)&Bl[wc + i * 16 + fr][kh * 8];
    }
#pragma unroll
    for (int i = 0; i < 4; ++i)
#pragma unroll
      for (int j = 0; j < 4; ++j) {
        acc[i][j] = __builtin_amdgcn_mfma_f32_16x16x32_bf16(ah[i], bh[j], acc[i][j], 0, 0, 0);
        acc[i][j] = __builtin_amdgcn_mfma_f32_16x16x32_bf16(ah[i], bl[j], acc[i][j], 0, 0, 0);
        acc[i][j] = __builtin_amdgcn_mfma_f32_16x16x32_bf16(al[i], bh[j], acc[i][j], 0, 0, 0);
      }
  }

  const int ll_ = llen[b], rl_ = rlen[b];
#pragma unroll
  for (int i = 0; i < 4; ++i) {
#pragma unroll
    for (int q = 0; q < 4; ++q) {
      int l = l0 + wr + i * 16 + kh * 4 + q;
      float lm = (l < ll_) ? 1.f : 0.f;
      float* orow = att + ((size_t)b * LL + l) * RR + r0 + wc;
#pragma unroll
      for (int j = 0; j < 4; ++j) {
        int r = r0 + wc + j * 16 + fr;
        float m = (r < rl_) ? lm : 0.f;
        orow[j * 16 + fr] = acc[i][j][q] * m;
      }
    }
  }
}

// ---------------- wave reduce helpers ----------------
__device__ __forceinline__ float wmaxf(float v) {
#pragma unroll
  for (int m = 32; m; m >>= 1) v = fmaxf(v, __shfl_xor(v, m, 64));
  return v;
}
__device__ __forceinline__ float wsumf(float v) {
#pragma unroll
  for (int m = 32; m; m >>= 1) v += __shfl_xor(v, m, 64);
  return v;
}

// ---------------- l-side stats ----------------
__global__ __launch_bounds__(256) void stats_rows(const float* __restrict__ att,
    const int* __restrict__ llen, const int* __restrict__ rlen,
    float* __restrict__ w_out, float* __restrict__ an_out, int* __restrict__ idx_out) {
  const int lane = threadIdx.x & 63;
  const int row  = blockIdx.x * 4 + (threadIdx.x >> 6);  // row = b*512 + l
  const int b = row >> 9, l = row & 511;
  const int rl_ = rlen[b], ll_ = llen[b];
  const float* base = att + (size_t)row * RR;
  float s[8];
#pragma unroll
  for (int j = 0; j < 8; ++j) {
    int r = lane + 64*j;
    float v = base[r];
    s[j] = (r < rl_) ? v : v - 10.f;
  }
  float M = -1e30f;
#pragma unroll
  for (int j = 0; j < 8; ++j) M = fmaxf(M, s[j]);
  M = wmaxf(M);
  float e[8]; float z0 = 0.f, zv = 0.f;
  float bv = -1e30f; int bi = 0;
#pragma unroll
  for (int j = 0; j < 8; ++j) {
    int r = lane + 64*j;
    float ej = __expf(s[j] - M);
    z0 += ej;
    bool valid = (r < rl_);
    float evj = valid ? ej : 0.f;
    e[j] = evj;
    zv += evj;
    if (valid && evj > bv) { bv = evj; bi = r; }
  }
  z0 = wsumf(z0); zv = wsumf(zv);
  const float S = zv / z0;
  const float inv = 1.f / (S + 1e-13f);
  const float c = inv / z0;
  float q2 = 0.f;
#pragma unroll
  for (int j = 0; j < 8; ++j) { float q = e[j] * c; q2 += q * q; }
  q2 = wsumf(q2);
#pragma unroll
  for (int m = 32; m; m >>= 1) {
    float ov = __shfl_xor(bv, m, 64);
    int   oi = __shfl_xor(bi, m, 64);
    if (ov > bv || (ov == bv && oi < bi)) { bv = ov; bi = oi; }
  }
  if (lane == 0) {
    float rlf = (float)rl_;
    float sumq = S * inv;
    float mean = sumq / rlf;
    float var  = q2 / rlf - mean * mean;
    float wv   = var / fmaxf(mean, 0.001f);
    float qmax = bv * c;
    float an   = qmax / fmaxf(qmax, 0.001f);
    w_out[row]  = wv;
    an_out[row] = an;
    idx_out[row] = (l < ll_) ? bi : 0;
  }
}

// ---------------- r-side stats ----------------
__global__ __launch_bounds__(256) void stats_cols(const float* __restrict__ att,
    const int* __restrict__ llen, const int* __restrict__ rlen,
    float* __restrict__ w_out, float* __restrict__ an_out, int* __restrict__ idx_out) {
  __shared__ float mM[4][64], mZ[4][64], mZv[4][64], mQ[4][64], mB[4][64];
  __shared__ int   mI[4][64];
  const int b  = blockIdx.x >> 3;
  const int r0 = (blockIdx.x & 7) * 64;
  const int t  = threadIdx.x;
  const int cl = t & 63;
  const int part = t >> 6;
  const int col = r0 + cl;
  const int ll_ = llen[b], rl_ = rlen[b];
  const float* base = att + ((size_t)b * LL) * RR + col;
  float M = -1e30f, Z = 0.f, Zv = 0.f, Q = 0.f, bS = -1e30f;
  int bI = 0;
  const int l0 = part * 128;
  for (int li = 0; li < 128; ++li) {
    int l = l0 + li;
    float v = base[(size_t)l * RR];
    bool lmv = (l < ll_);
    float s = lmv ? v : v - 10.f;
    if (s > M) {
      float sc = __expf(M - s);
      Z *= sc; Zv *= sc; Q *= sc * sc;
      M = s;
    }
    float ej = __expf(s - M);
    Z += ej;
    if (lmv) {
      Zv += ej; Q += ej * ej;
      if (s > bS) { bS = s; bI = l; }
    }
  }
  mM[part][cl] = M; mZ[part][cl] = Z; mZv[part][cl] = Zv;
  mQ[part][cl] = Q; mB[part][cl] = bS; mI[part][cl] = bI;
  __syncthreads();
  if (t < 64) {
    float M0 = mM[0][t], Z0 = mZ[0][t], Zv0 = mZv[0][t], Q0 = mQ[0][t], bS0 = mB[0][t];
    int bI0 = mI[0][t];
#pragma unroll
    for (int p = 1; p < 4; ++p) {
      float M1 = mM[p][t], Z1 = mZ[p][t], Zv1 = mZv[p][t], Q1 = mQ[p][t], bS1 = mB[p][t];
      int bI1 = mI[p][t];
      float Mn = fmaxf(M0, M1);
      float c0 = __expf(M0 - Mn), c1 = __expf(M1 - Mn);
      Z0  = Z0 * c0 + Z1 * c1;
      Zv0 = Zv0 * c0 + Zv1 * c1;
      Q0  = Q0 * c0 * c0 + Q1 * c1 * c1;
      M0 = Mn;
      if (bS1 > bS0) { bS0 = bS1; bI0 = bI1; }
    }
    const float S = Zv0 / Z0;
    const float inv = 1.f / (S + 1e-13f);
    float llf = (float)ll_;
    float sumq = S * inv;
    float mean = sumq / llf;
    float sumq2 = Q0 / (Z0 * Z0) * inv * inv;
    float var = sumq2 / llf - mean * mean;
    float wv = var / fmaxf(mean, 0.001f);
    float qmax = __expf(bS0 - M0) / Z0 * inv;
    float an = qmax / fmaxf(qmax, 0.001f);
    int c_ = r0 + t;
    w_out[b * RR + c_]  = wv;
    an_out[b * RR + c_] = an;
    idx_out[b * RR + c_] = (c_ < rl_) ? bI0 : 0;
  }
}

// ---------------- prep: Wconv [100][512] -> bf16 hi/lo [112][512] (f-major, zero-padded) ------
__global__ void prep_w(const float* __restrict__ Wconv,
                       unsigned short* __restrict__ Whg, unsigned short* __restrict__ Wlg) {
  int i = blockIdx.x * 256 + threadIdx.x;
  if (i < FP * DD) {
    int f = i >> 9;
    float w = (f < FC) ? Wconv[i] : 0.f;
    unsigned short h = bf16rne(w);
    unsigned short l = bf16rne(w - bf16tof(h));
    Whg[i] = h; Wlg[i] = l;
  }
}

// ---------------- conv + relu + masked maxpool via bf16 hi/lo MFMA ----------------
// Per block: one (side,b,s-chunk of 128). A = w*|x - a*y| computed on the fly.
__global__ __launch_bounds__(256) void conv_pool_mfma(const float* __restrict__ lv,
    const float* __restrict__ rv,
    const float* __restrict__ lwv, const float* __restrict__ lan, const int* __restrict__ lidx,
    const float* __restrict__ rwv, const float* __restrict__ ran, const int* __restrict__ ridx,
    const int* __restrict__ llen, const int* __restrict__ rlen,
    const unsigned short* __restrict__ Whg, const unsigned short* __restrict__ Wlg,
    const float* __restrict__ bconv, float* __restrict__ feat) {
  __shared__ unsigned short Ah[128][40];
  __shared__ unsigned short Al[128][40];
  __shared__ unsigned short Wh[FP][40];
  __shared__ unsigned short Wl[FP][40];
  __shared__ float pool[4][FP];
  __shared__ float ppw[128], ppa[128];
  __shared__ int   ppi[128], ppv[128];

  // XCD swizzle: 512 blocks -> 64 contiguous wids per XCD (same-b s-chunks colocated)
  const int bid = blockIdx.x;
  const int wid = (bid & 7) * 64 + (bid >> 3);
  const int side = wid >> 8;
  const int b    = (wid >> 2) & 63;
  const int s0   = (wid & 3) * 128;

  const int t = threadIdx.x;
  const float* x; const float* y; const float* wb; const float* ab; const int* ib; int plen;
  if (side == 0) { x = lv; y = rv; wb = lwv; ab = lan; ib = lidx; plen = llen[b]; }
  else           { x = rv; y = lv; wb = rwv; ab = ran; ib = ridx; plen = rlen[b]; }

  if (t < 128) {
    int pos = s0 + t;
    ppw[t] = wb[b * 512 + pos];
    ppa[t] = ab[b * 512 + pos];
    ppi[t] = ib[b * 512 + pos];
    ppv[t] = (pos < plen) ? 1 : 0;
  }
  __syncthreads();

  // staging role: thread t handles (pos = t>>1, 16 d values at half*16)
  const int pos  = t >> 1;
  const int half = t & 1;
  const float w_ = ppw[pos];
  const float a_ = ppa[pos];
  const int   yi = ppi[pos];
  const float* xp = x + (size_t)(s0 + pos) * BD + b * DD + half * 16;
  const float* yp = y + (size_t)yi * BD + b * DD + half * 16;

  float4 xv[4], yv[4];
#pragma unroll
  for (int q = 0; q < 4; ++q) {
    xv[q] = *(const float4*)(xp + q * 4);
    yv[q] = *(const float4*)(yp + q * 4);
  }

  const int lane = t & 63;
  const int wvi = t >> 6;        // wave 0..3
  const int m0 = wvi * 32;
  const int fr = lane & 15;
  const int kh = lane >> 4;

  f32x4 acc[2][7];
#pragma unroll
  for (int i = 0; i < 2; ++i)
#pragma unroll
    for (int j = 0; j < 7; ++j) acc[i][j] = (f32x4){0.f, 0.f, 0.f, 0.f};

  for (int it = 0; it < 16; ++it) {
    const int k0 = it * 32;
    __syncthreads();
    // A tile: compute diff, split hi/lo
#pragma unroll
    for (int q = 0; q < 4; ++q) {
      float d0 = w_ * fabsf(xv[q].x - a_ * yv[q].x);
      float d1 = w_ * fabsf(xv[q].y - a_ * yv[q].y);
      float d2 = w_ * fabsf(xv[q].z - a_ * yv[q].z);
      float d3 = w_ * fabsf(xv[q].w - a_ * yv[q].w);
      ushort4 h, l;
      h.x = bf16rne(d0); l.x = bf16rne(d0 - bf16tof(h.x));
      h.y = bf16rne(d1); l.y = bf16rne(d1 - bf16tof(h.y));
      h.z = bf16rne(d2); l.z = bf16rne(d2 - bf16tof(h.z));
      h.w = bf16rne(d3); l.w = bf16rne(d3 - bf16tof(h.w));
      *(ushort4*)&Ah[pos][half * 16 + q * 4] = h;
      *(ushort4*)&Al[pos][half * 16 + q * 4] = l;
    }
    // W tile: [f][k] layout straight from global (f-major)
#pragma unroll
    for (int rep = 0; rep < 2; ++rep) {
      int idx = t + rep * 256;
      if (idx < FP * 4) {
        int f = idx >> 2, q = idx & 3;
        *(ulonglong2*)&Wh[f][q * 8] = *(const ulonglong2*)&Whg[f * DD + k0 + q * 8];
        *(ulonglong2*)&Wl[f][q * 8] = *(const ulonglong2*)&Wlg[f * DD + k0 + q * 8];
      }
    }
    // prefetch next chunk's x/y into regs (hides HBM under MFMA phase)
    if (it < 15) {
      const float* xn = xp + k0 + 32;
      const float* yn = yp + k0 + 32;
#pragma unroll
      for (int q = 0; q < 4; ++q) {
        xv[q] = *(const float4*)(xn + q * 4);
        yv[q] = *(const float4*)(yn + q * 4);
      }
    }
    __syncthreads();

    bf16x8 ah[2], al[2];
#pragma unroll
    for (int i = 0; i < 2; ++i) {
      ah[i] = *(const bf16x8*)&Ah[m0 + i * 16 + fr][kh * 8];
      al[i] = *(const bf16x8*)&Al[m0 + i * 16 + fr][kh * 8];
    }
#pragma unroll
    for (int j = 0; j < 7; ++j) {
      bf16x8 bh = *(const bf16x8*)&Wh[j * 16 + fr][kh * 8];
      bf16x8 bl = *(const bf16x8*)&Wl[j * 16 + fr][kh * 8];
#pragma unroll
      for (int i = 0; i < 2; ++i) {
        acc[i][j] = __builtin_amdgcn_mfma_f32_16x16x32_bf16(ah[i], bh, acc[i][j], 0, 0, 0);
        acc[i][j] = __builtin_amdgcn_mfma_f32_16x16x32_bf16(ah[i], bl, acc[i][j], 0, 0, 0);
        acc[i][j] = __builtin_amdgcn_mfma_f32_16x16x32_bf16(al[i], bh, acc[i][j], 0, 0, 0);
      }
    }
  }

  // epilogue: bias + relu + validity + maxpool
#pragma unroll
  for (int j = 0; j < 7; ++j) {
    int f = j * 16 + fr;
    float bcv = (f < FC) ? bconv[f] : 0.f;
    float vmax = -1e30f;
#pragma unroll
    for (int i = 0; i < 2; ++i) {
#pragma unroll
      for (int q = 0; q < 4; ++q) {
        int sl = m0 + i * 16 + kh * 4 + q;
        if (ppv[sl]) vmax = fmaxf(vmax, fmaxf(acc[i][j][q] + bcv, 0.f));
      }
    }
    vmax = fmaxf(vmax, __shfl_xor(vmax, 16, 64));
    vmax = fmaxf(vmax, __shfl_xor(vmax, 32, 64));
    if (lane < 16) pool[wvi][f] = vmax;
  }
  __syncthreads();
  if (t < FC) {
    float v = fmaxf(fmaxf(pool[0][t], pool[1][t]), fmaxf(pool[2][t], pool[3][t]));
    if (v > -1e29f) atomicMax((int*)&feat[b * 200 + side * FC + t], __float_as_int(v));
  }
}

// ---------------- final dense [B,200] x [200,60] + relu ----------------
__global__ void dense_out(const float* __restrict__ feat, const float* __restrict__ Wd,
                          const float* __restrict__ bd, float* __restrict__ out) {
  int b = blockIdx.x, h = threadIdx.x;
  if (h < HH) {
    float s = bd[h];
    const float* fb = feat + b * 200;
    const float* wr = Wd + h * 200;
    for (int k = 0; k < 200; ++k) s += fb[k] * wr[k];
    out[b * HH + h] = fmaxf(s, 0.f);
  }
}

extern "C" void kernel_launch(void* const* d_in, const int* in_sizes, int n_in,
                              void* d_out, int out_size, void* d_ws, size_t ws_size,
                              hipStream_t stream) {
  (void)in_sizes; (void)n_in; (void)out_size; (void)ws_size;
  const int*   llen  = (const int*)d_in[0];
  const float* lv    = (const float*)d_in[1];
  const int*   rlen  = (const int*)d_in[2];
  const float* rv    = (const float*)d_in[3];
  const float* Wconv = (const float*)d_in[4];
  const float* bconv = (const float*)d_in[5];
  const float* Wd    = (const float*)d_in[6];
  const float* bd    = (const float*)d_in[7];
  float* out = (float*)d_out;
  char* ws = (char*)d_ws;
  size_t off = 0;
  float* att = (float*)(ws + off); off += (size_t)BB * LL * RR * 4;  // 64 MiB
  unsigned short* Whg = (unsigned short*)(ws + off); off += (size_t)FP * DD * 2;
  unsigned short* Wlg = (unsigned short*)(ws + off); off += (size_t)FP * DD * 2;
  float* lwv = (float*)(ws + off); off += (size_t)BB * LL * 4;
  float* lan = (float*)(ws + off); off += (size_t)BB * LL * 4;
  int*   lidx= (int*)  (ws + off); off += (size_t)BB * LL * 4;
  float* rwv = (float*)(ws + off); off += (size_t)BB * RR * 4;
  float* ran = (float*)(ws + off); off += (size_t)BB * RR * 4;
  int*   ridx= (int*)  (ws + off); off += (size_t)BB * RR * 4;
  float* feat= (float*)(ws + off); off += (size_t)BB * 200 * 4;

  hipMemsetAsync(feat, 0, BB * 200 * 4, stream);
  prep_w<<<(FP * DD + 255) / 256, 256, 0, stream>>>(Wconv, Whg, Wlg);
  gemm_att<<<dim3(1024), 256, 0, stream>>>(lv, rv, llen, rlen, att);
  stats_rows<<<BB * LL / 4, 256, 0, stream>>>(att, llen, rlen, lwv, lan, lidx);
  stats_cols<<<BB * 8, 256, 0, stream>>>(att, llen, rlen, rwv, ran, ridx);
  conv_pool_mfma<<<dim3(512), 256, 0, stream>>>(lv, rv, lwv, lan, lidx,
                                                rwv, ran, ridx, llen, rlen,
                                                Whg, Wlg, bconv, feat);
  dense_out<<<BB, 64, 0, stream>>>(feat, Wd, bd, out);
}

// Round 4
// 174.045 us; speedup vs baseline: 2.8698x; 1.0468x over previous
//
#include <hip/hip_runtime.h>
#include <math.h>

#define BB 64
#define LL 512
#define RR 512
#define DD 512
#define FC 100
#define FP 112
#define HH 60
#define BD (BB*DD)

typedef __attribute__((ext_vector_type(8))) short bf16x8;
typedef __attribute__((ext_vector_type(4))) float f32x4;

__device__ __forceinline__ unsigned short bf16rne(float x) {
  unsigned u = __float_as_uint(x);
  return (unsigned short)((u + 0x7fffu + ((u >> 16) & 1u)) >> 16);
}
__device__ __forceinline__ float bf16tof(unsigned short h) {
  return __uint_as_float((unsigned)h << 16);
}

// Truncating hi/lo bf16 split of 2 floats, packed via v_perm_b32.
// h2 = [hi16(x1) | hi16(x0)], l2 = [hi16(r1) | hi16(r0)], r = x - trunc16(x).
// Representation error <= 2^-16 relative — below the dropped al*bl term.
__device__ __forceinline__ void split2(float x0, float x1, unsigned& h2, unsigned& l2) {
  unsigned u0 = __float_as_uint(x0), u1 = __float_as_uint(x1);
  h2 = __builtin_amdgcn_perm(u1, u0, 0x07060302u);
  float r0 = x0 - __uint_as_float(u0 & 0xffff0000u);
  float r1 = x1 - __uint_as_float(u1 & 0xffff0000u);
  l2 = __builtin_amdgcn_perm(__float_as_uint(r1), __float_as_uint(r0), 0x07060302u);
}

// ---------------- batched attention GEMM via bf16 hi/lo split MFMA ----------------
__global__ __launch_bounds__(256) void gemm_att(const float* __restrict__ lv,
                                                const float* __restrict__ rv,
                                                const int* __restrict__ llen,
                                                const int* __restrict__ rlen,
                                                float* __restrict__ att) {
  __shared__ unsigned short Ah[128][40];
  __shared__ unsigned short Al[128][40];
  __shared__ unsigned short Bh[128][40];
  __shared__ unsigned short Bl[128][40];

  const int bid = blockIdx.x;
  const int wid = (bid & 7) * 128 + (bid >> 3);
  const int b  = wid >> 4;
  const int l0 = ((wid >> 2) & 3) * 128;
  const int r0 = (wid & 3) * 128;

  const int t = threadIdx.x;
  const int row16 = t >> 3;        // 0..31
  const int kq = (t & 7) * 4;      // 0,4,..28 (ushort offset)

  const float* Abase = lv + (size_t)(l0 + row16) * BD + b * DD + kq;
  const float* Bbase = rv + (size_t)(r0 + row16) * BD + b * DD + kq;

  float4 pa[4], pb[4];
#pragma unroll
  for (int p = 0; p < 4; ++p) {
    pa[p] = *(const float4*)(Abase + (size_t)p * 32 * BD);
    pb[p] = *(const float4*)(Bbase + (size_t)p * 32 * BD);
  }

  const int lane = t & 63;
  const int wv = t >> 6;
  const int wr = (wv >> 1) * 64;
  const int wc = (wv & 1) * 64;
  const int fr = lane & 15;
  const int kh = lane >> 4;        // 0..3

  f32x4 acc[4][4];
#pragma unroll
  for (int i = 0; i < 4; ++i)
#pragma unroll
    for (int j = 0; j < 4; ++j) acc[i][j] = (f32x4){0.f, 0.f, 0.f, 0.f};

  for (int it = 0; it < 16; ++it) {
    __syncthreads();
#pragma unroll
    for (int p = 0; p < 4; ++p) {
      int rr = p * 32 + row16;
      unsigned h01, l01, h23, l23;
      split2(pa[p].x, pa[p].y, h01, l01);
      split2(pa[p].z, pa[p].w, h23, l23);
      *(uint2*)&Ah[rr][kq] = make_uint2(h01, h23);
      *(uint2*)&Al[rr][kq] = make_uint2(l01, l23);
      split2(pb[p].x, pb[p].y, h01, l01);
      split2(pb[p].z, pb[p].w, h23, l23);
      *(uint2*)&Bh[rr][kq] = make_uint2(h01, h23);
      *(uint2*)&Bl[rr][kq] = make_uint2(l01, l23);
    }
    if (it < 15) {
      const float* An = Abase + (it + 1) * 32;
      const float* Bn = Bbase + (it + 1) * 32;
#pragma unroll
      for (int p = 0; p < 4; ++p) {
        pa[p] = *(const float4*)(An + (size_t)p * 32 * BD);
        pb[p] = *(const float4*)(Bn + (size_t)p * 32 * BD);
      }
    }
    __syncthreads();

    bf16x8 ah[4], al[4], bh[4], bl[4];
#pragma unroll
    for (int i = 0; i < 4; ++i) {
      ah[i] = *(const bf16x8*)&Ah[wr + i * 16 + fr][kh * 8];
      al[i] = *(const bf16x8*)&Al[wr + i * 16 + fr][kh * 8];
      bh[i] = *(const bf16x8*)&Bh[wc + i * 16 + fr][kh * 8];
      bl[i] = *(const bf16x8*)&Bl[wc + i * 16 + fr][kh * 8];
    }
#pragma unroll
    for (int i = 0; i < 4; ++i)
#pragma unroll
      for (int j = 0; j < 4; ++j) {
        acc[i][j] = __builtin_amdgcn_mfma_f32_16x16x32_bf16(ah[i], bh[j], acc[i][j], 0, 0, 0);
        acc[i][j] = __builtin_amdgcn_mfma_f32_16x16x32_bf16(ah[i], bl[j], acc[i][j], 0, 0, 0);
        acc[i][j] = __builtin_amdgcn_mfma_f32_16x16x32_bf16(al[i], bh[j], acc[i][j], 0, 0, 0);
      }
  }

  const int ll_ = llen[b], rl_ = rlen[b];
#pragma unroll
  for (int i = 0; i < 4; ++i) {
#pragma unroll
    for (int q = 0; q < 4; ++q) {
      int l = l0 + wr + i * 16 + kh * 4 + q;
      float lm = (l < ll_) ? 1.f : 0.f;
      float* orow = att + ((size_t)b * LL + l) * RR + r0 + wc;
#pragma unroll
      for (int j = 0; j < 4; ++j) {
        int r = r0 + wc + j * 16 + fr;
        float m = (r < rl_) ? lm : 0.f;
        orow[j * 16 + fr] = acc[i][j][q] * m;
      }
    }
  }
}

// ---------------- wave reduce helpers ----------------
__device__ __forceinline__ float wmaxf(float v) {
#pragma unroll
  for (int m = 32; m; m >>= 1) v = fmaxf(v, __shfl_xor(v, m, 64));
  return v;
}
__device__ __forceinline__ float wsumf(float v) {
#pragma unroll
  for (int m = 32; m; m >>= 1) v += __shfl_xor(v, m, 64);
  return v;
}

// ---------------- l-side stats ----------------
__global__ __launch_bounds__(256) void stats_rows(const float* __restrict__ att,
    const int* __restrict__ llen, const int* __restrict__ rlen,
    float* __restrict__ w_out, float* __restrict__ an_out, int* __restrict__ idx_out) {
  const int lane = threadIdx.x & 63;
  const int row  = blockIdx.x * 4 + (threadIdx.x >> 6);  // row = b*512 + l
  const int b = row >> 9, l = row & 511;
  const int rl_ = rlen[b], ll_ = llen[b];
  const float* base = att + (size_t)row * RR;
  float s[8];
#pragma unroll
  for (int j = 0; j < 8; ++j) {
    int r = lane + 64*j;
    float v = base[r];
    s[j] = (r < rl_) ? v : v - 10.f;
  }
  float M = -1e30f;
#pragma unroll
  for (int j = 0; j < 8; ++j) M = fmaxf(M, s[j]);
  M = wmaxf(M);
  float e[8]; float z0 = 0.f, zv = 0.f;
  float bv = -1e30f; int bi = 0;
#pragma unroll
  for (int j = 0; j < 8; ++j) {
    int r = lane + 64*j;
    float ej = __expf(s[j] - M);
    z0 += ej;
    bool valid = (r < rl_);
    float evj = valid ? ej : 0.f;
    e[j] = evj;
    zv += evj;
    if (valid && evj > bv) { bv = evj; bi = r; }
  }
  z0 = wsumf(z0); zv = wsumf(zv);
  const float S = zv / z0;
  const float inv = 1.f / (S + 1e-13f);
  const float c = inv / z0;
  float q2 = 0.f;
#pragma unroll
  for (int j = 0; j < 8; ++j) { float q = e[j] * c; q2 += q * q; }
  q2 = wsumf(q2);
#pragma unroll
  for (int m = 32; m; m >>= 1) {
    float ov = __shfl_xor(bv, m, 64);
    int   oi = __shfl_xor(bi, m, 64);
    if (ov > bv || (ov == bv && oi < bi)) { bv = ov; bi = oi; }
  }
  if (lane == 0) {
    float rlf = (float)rl_;
    float sumq = S * inv;
    float mean = sumq / rlf;
    float var  = q2 / rlf - mean * mean;
    float wv   = var / fmaxf(mean, 0.001f);
    float qmax = bv * c;
    float an   = qmax / fmaxf(qmax, 0.001f);
    w_out[row]  = wv;
    an_out[row] = an;
    idx_out[row] = (l < ll_) ? bi : 0;
  }
}

// ---------------- r-side stats ----------------
__global__ __launch_bounds__(256) void stats_cols(const float* __restrict__ att,
    const int* __restrict__ llen, const int* __restrict__ rlen,
    float* __restrict__ w_out, float* __restrict__ an_out, int* __restrict__ idx_out) {
  __shared__ float mM[4][64], mZ[4][64], mZv[4][64], mQ[4][64], mB[4][64];
  __shared__ int   mI[4][64];
  const int b  = blockIdx.x >> 3;
  const int r0 = (blockIdx.x & 7) * 64;
  const int t  = threadIdx.x;
  const int cl = t & 63;
  const int part = t >> 6;
  const int col = r0 + cl;
  const int ll_ = llen[b], rl_ = rlen[b];
  const float* base = att + ((size_t)b * LL) * RR + col;
  float M = -1e30f, Z = 0.f, Zv = 0.f, Q = 0.f, bS = -1e30f;
  int bI = 0;
  const int l0 = part * 128;
  for (int li = 0; li < 128; ++li) {
    int l = l0 + li;
    float v = base[(size_t)l * RR];
    bool lmv = (l < ll_);
    float s = lmv ? v : v - 10.f;
    if (s > M) {
      float sc = __expf(M - s);
      Z *= sc; Zv *= sc; Q *= sc * sc;
      M = s;
    }
    float ej = __expf(s - M);
    Z += ej;
    if (lmv) {
      Zv += ej; Q += ej * ej;
      if (s > bS) { bS = s; bI = l; }
    }
  }
  mM[part][cl] = M; mZ[part][cl] = Z; mZv[part][cl] = Zv;
  mQ[part][cl] = Q; mB[part][cl] = bS; mI[part][cl] = bI;
  __syncthreads();
  if (t < 64) {
    float M0 = mM[0][t], Z0 = mZ[0][t], Zv0 = mZv[0][t], Q0 = mQ[0][t], bS0 = mB[0][t];
    int bI0 = mI[0][t];
#pragma unroll
    for (int p = 1; p < 4; ++p) {
      float M1 = mM[p][t], Z1 = mZ[p][t], Zv1 = mZv[p][t], Q1 = mQ[p][t], bS1 = mB[p][t];
      int bI1 = mI[p][t];
      float Mn = fmaxf(M0, M1);
      float c0 = __expf(M0 - Mn), c1 = __expf(M1 - Mn);
      Z0  = Z0 * c0 + Z1 * c1;
      Zv0 = Zv0 * c0 + Zv1 * c1;
      Q0  = Q0 * c0 * c0 + Q1 * c1 * c1;
      M0 = Mn;
      if (bS1 > bS0) { bS0 = bS1; bI0 = bI1; }
    }
    const float S = Zv0 / Z0;
    const float inv = 1.f / (S + 1e-13f);
    float llf = (float)ll_;
    float sumq = S * inv;
    float mean = sumq / llf;
    float sumq2 = Q0 / (Z0 * Z0) * inv * inv;
    float var = sumq2 / llf - mean * mean;
    float wv = var / fmaxf(mean, 0.001f);
    float qmax = __expf(bS0 - M0) / Z0 * inv;
    float an = qmax / fmaxf(qmax, 0.001f);
    int c_ = r0 + t;
    w_out[b * RR + c_]  = wv;
    an_out[b * RR + c_] = an;
    idx_out[b * RR + c_] = (c_ < rl_) ? bI0 : 0;
  }
}

// ---------------- prep: Wconv [100][512] -> bf16 hi/lo [112][512] (f-major, zero-padded) ------
__global__ void prep_w(const float* __restrict__ Wconv,
                       unsigned short* __restrict__ Whg, unsigned short* __restrict__ Wlg) {
  int i = blockIdx.x * 256 + threadIdx.x;
  if (i < FP * DD) {
    int f = i >> 9;
    float w = (f < FC) ? Wconv[i] : 0.f;
    unsigned short h = bf16rne(w);
    unsigned short l = bf16rne(w - bf16tof(h));
    Whg[i] = h; Wlg[i] = l;
  }
}

// ---------------- conv + relu + masked maxpool via bf16 hi/lo MFMA ----------------
__global__ __launch_bounds__(256) void conv_pool_mfma(const float* __restrict__ lv,
    const float* __restrict__ rv,
    const float* __restrict__ lwv, const float* __restrict__ lan, const int* __restrict__ lidx,
    const float* __restrict__ rwv, const float* __restrict__ ran, const int* __restrict__ ridx,
    const int* __restrict__ llen, const int* __restrict__ rlen,
    const unsigned short* __restrict__ Whg, const unsigned short* __restrict__ Wlg,
    const float* __restrict__ bconv, float* __restrict__ feat) {
  __shared__ unsigned short Ah[128][40];
  __shared__ unsigned short Al[128][40];
  __shared__ unsigned short Wh[FP][40];
  __shared__ unsigned short Wl[FP][40];
  __shared__ float pool[4][FP];
  __shared__ float ppw[128], ppa[128];
  __shared__ int   ppi[128], ppv[128];

  const int bid = blockIdx.x;
  const int wid = (bid & 7) * 64 + (bid >> 3);
  const int side = wid >> 8;
  const int b    = (wid >> 2) & 63;
  const int s0   = (wid & 3) * 128;

  const int t = threadIdx.x;
  const float* x; const float* y; const float* wb; const float* ab; const int* ib; int plen;
  if (side == 0) { x = lv; y = rv; wb = lwv; ab = lan; ib = lidx; plen = llen[b]; }
  else           { x = rv; y = lv; wb = rwv; ab = ran; ib = ridx; plen = rlen[b]; }

  if (t < 128) {
    int pos = s0 + t;
    ppw[t] = wb[b * 512 + pos];
    ppa[t] = ab[b * 512 + pos];
    ppi[t] = ib[b * 512 + pos];
    ppv[t] = (pos < plen) ? 1 : 0;
  }
  __syncthreads();

  const int pos  = t >> 1;
  const int half = t & 1;
  const float w_ = ppw[pos];
  const float a_ = ppa[pos];
  const int   yi = ppi[pos];
  const float* xp = x + (size_t)(s0 + pos) * BD + b * DD + half * 16;
  const float* yp = y + (size_t)yi * BD + b * DD + half * 16;

  float4 xv[4], yv[4];
#pragma unroll
  for (int q = 0; q < 4; ++q) {
    xv[q] = *(const float4*)(xp + q * 4);
    yv[q] = *(const float4*)(yp + q * 4);
  }

  const int lane = t & 63;
  const int wvi = t >> 6;        // wave 0..3
  const int m0 = wvi * 32;
  const int fr = lane & 15;
  const int kh = lane >> 4;

  f32x4 acc[2][7];
#pragma unroll
  for (int i = 0; i < 2; ++i)
#pragma unroll
    for (int j = 0; j < 7; ++j) acc[i][j] = (f32x4){0.f, 0.f, 0.f, 0.f};

  for (int it = 0; it < 16; ++it) {
    const int k0 = it * 32;
    __syncthreads();
#pragma unroll
    for (int q = 0; q < 2; ++q) {
      float d0 = w_ * fabsf(xv[2*q].x   - a_ * yv[2*q].x);
      float d1 = w_ * fabsf(xv[2*q].y   - a_ * yv[2*q].y);
      float d2 = w_ * fabsf(xv[2*q].z   - a_ * yv[2*q].z);
      float d3 = w_ * fabsf(xv[2*q].w   - a_ * yv[2*q].w);
      float d4 = w_ * fabsf(xv[2*q+1].x - a_ * yv[2*q+1].x);
      float d5 = w_ * fabsf(xv[2*q+1].y - a_ * yv[2*q+1].y);
      float d6 = w_ * fabsf(xv[2*q+1].z - a_ * yv[2*q+1].z);
      float d7 = w_ * fabsf(xv[2*q+1].w - a_ * yv[2*q+1].w);
      unsigned h01, l01, h23, l23, h45, l45, h67, l67;
      split2(d0, d1, h01, l01);
      split2(d2, d3, h23, l23);
      split2(d4, d5, h45, l45);
      split2(d6, d7, h67, l67);
      *(uint4*)&Ah[pos][half * 16 + q * 8] = make_uint4(h01, h23, h45, h67);
      *(uint4*)&Al[pos][half * 16 + q * 8] = make_uint4(l01, l23, l45, l67);
    }
#pragma unroll
    for (int rep = 0; rep < 2; ++rep) {
      int idx = t + rep * 256;
      if (idx < FP * 4) {
        int f = idx >> 2, q = idx & 3;
        *(ulonglong2*)&Wh[f][q * 8] = *(const ulonglong2*)&Whg[f * DD + k0 + q * 8];
        *(ulonglong2*)&Wl[f][q * 8] = *(const ulonglong2*)&Wlg[f * DD + k0 + q * 8];
      }
    }
    if (it < 15) {
      const float* xn = xp + k0 + 32;
      const float* yn = yp + k0 + 32;
#pragma unroll
      for (int q = 0; q < 4; ++q) {
        xv[q] = *(const float4*)(xn + q * 4);
        yv[q] = *(const float4*)(yn + q * 4);
      }
    }
    __syncthreads();

    bf16x8 ah[2], al[2];
#pragma unroll
    for (int i = 0; i < 2; ++i) {
      ah[i] = *(const bf16x8*)&Ah[m0 + i * 16 + fr][kh * 8];
      al[i] = *(const bf16x8*)&Al[m0 + i * 16 + fr][kh * 8];
    }
#pragma unroll
    for (int j = 0; j < 7; ++j) {
      bf16x8 bh = *(const bf16x8*)&Wh[j * 16 + fr][kh * 8];
      bf16x8 bl = *(const bf16x8*)&Wl[j * 16 + fr][kh * 8];
#pragma unroll
      for (int i = 0; i < 2; ++i) {
        acc[i][j] = __builtin_amdgcn_mfma_f32_16x16x32_bf16(ah[i], bh, acc[i][j], 0, 0, 0);
        acc[i][j] = __builtin_amdgcn_mfma_f32_16x16x32_bf16(ah[i], bl, acc[i][j], 0, 0, 0);
        acc[i][j] = __builtin_amdgcn_mfma_f32_16x16x32_bf16(al[i], bh, acc[i][j], 0, 0, 0);
      }
    }
  }

  // epilogue: bias + relu + validity + maxpool
#pragma unroll
  for (int j = 0; j < 7; ++j) {
    int f = j * 16 + fr;
    float bcv = (f < FC) ? bconv[f] : 0.f;
    float vmax = -1e30f;
#pragma unroll
    for (int i = 0; i < 2; ++i) {
#pragma unroll
      for (int q = 0; q < 4; ++q) {
        int sl = m0 + i * 16 + kh * 4 + q;
        if (ppv[sl]) vmax = fmaxf(vmax, fmaxf(acc[i][j][q] + bcv, 0.f));
      }
    }
    vmax = fmaxf(vmax, __shfl_xor(vmax, 16, 64));
    vmax = fmaxf(vmax, __shfl_xor(vmax, 32, 64));
    if (lane < 16) pool[wvi][f] = vmax;
  }
  __syncthreads();
  if (t < FC) {
    float v = fmaxf(fmaxf(pool[0][t], pool[1][t]), fmaxf(pool[2][t], pool[3][t]));
    if (v > -1e29f) atomicMax((int*)&feat[b * 200 + side * FC + t], __float_as_int(v));
  }
}

// ---------------- final dense [B,200] x [200,60] + relu ----------------
__global__ void dense_out(const float* __restrict__ feat, const float* __restrict__ Wd,
                          const float* __restrict__ bd, float* __restrict__ out) {
  int b = blockIdx.x, h = threadIdx.x;
  if (h < HH) {
    float s = bd[h];
    const float* fb = feat + b * 200;
    const float* wr = Wd + h * 200;
    for (int k = 0; k < 200; ++k) s += fb[k] * wr[k];
    out[b * HH + h] = fmaxf(s, 0.f);
  }
}

extern "C" void kernel_launch(void* const* d_in, const int* in_sizes, int n_in,
                              void* d_out, int out_size, void* d_ws, size_t ws_size,
                              hipStream_t stream) {
  (void)in_sizes; (void)n_in; (void)out_size; (void)ws_size;
  const int*   llen  = (const int*)d_in[0];
  const float* lv    = (const float*)d_in[1];
  const int*   rlen  = (const int*)d_in[2];
  const float* rv    = (const float*)d_in[3];
  const float* Wconv = (const float*)d_in[4];
  const float* bconv = (const float*)d_in[5];
  const float* Wd    = (const float*)d_in[6];
  const float* bd    = (const float*)d_in[7];
  float* out = (float*)d_out;
  char* ws = (char*)d_ws;
  size_t off = 0;
  float* att = (float*)(ws + off); off += (size_t)BB * LL * RR * 4;  // 64 MiB
  unsigned short* Whg = (unsigned short*)(ws + off); off += (size_t)FP * DD * 2;
  unsigned short* Wlg = (unsigned short*)(ws + off); off += (size_t)FP * DD * 2;
  float* lwv = (float*)(ws + off); off += (size_t)BB * LL * 4;
  float* lan = (float*)(ws + off); off += (size_t)BB * LL * 4;
  int*   lidx= (int*)  (ws + off); off += (size_t)BB * LL * 4;
  float* rwv = (float*)(ws + off); off += (size_t)BB * RR * 4;
  float* ran = (float*)(ws + off); off += (size_t)BB * RR * 4;
  int*   ridx= (int*)  (ws + off); off += (size_t)BB * RR * 4;
  float* feat= (float*)(ws + off); off += (size_t)BB * 200 * 4;

  hipMemsetAsync(feat, 0, BB * 200 * 4, stream);
  prep_w<<<(FP * DD + 255) / 256, 256, 0, stream>>>(Wconv, Whg, Wlg);
  gemm_att<<<dim3(1024), 256, 0, stream>>>(lv, rv, llen, rlen, att);
  stats_rows<<<BB * LL / 4, 256, 0, stream>>>(att, llen, rlen, lwv, lan, lidx);
  stats_cols<<<BB * 8, 256, 0, stream>>>(att, llen, rlen, rwv, ran, ridx);
  conv_pool_mfma<<<dim3(512), 256, 0, stream>>>(lv, rv, lwv, lan, lidx,
                                                rwv, ran, ridx, llen, rlen,
                                                Whg, Wlg, bconv, feat);
  dense_out<<<BB, 64, 0, stream>>>(feat, Wd, bd, out);
}

// Round 5
// 171.700 us; speedup vs baseline: 2.9090x; 1.0137x over previous
//
#include <hip/hip_runtime.h>
#include <math.h>

#define BB 64
#define LL 512
#define RR 512
#define DD 512
#define FC 100
#define FP 112
#define HH 60
#define BD (BB*DD)

typedef __attribute__((ext_vector_type(8))) short bf16x8;
typedef __attribute__((ext_vector_type(4))) float f32x4;

__device__ __forceinline__ unsigned short bf16rne(float x) {
  unsigned u = __float_as_uint(x);
  return (unsigned short)((u + 0x7fffu + ((u >> 16) & 1u)) >> 16);
}
__device__ __forceinline__ float bf16tof(unsigned short h) {
  return __uint_as_float((unsigned)h << 16);
}

// Truncating hi/lo bf16 split of 2 floats, packed via v_perm_b32.
__device__ __forceinline__ void split2(float x0, float x1, unsigned& h2, unsigned& l2) {
  unsigned u0 = __float_as_uint(x0), u1 = __float_as_uint(x1);
  h2 = __builtin_amdgcn_perm(u1, u0, 0x07060302u);
  float r0 = x0 - __uint_as_float(u0 & 0xffff0000u);
  float r1 = x1 - __uint_as_float(u1 & 0xffff0000u);
  l2 = __builtin_amdgcn_perm(__float_as_uint(r1), __float_as_uint(r0), 0x07060302u);
}

// ---------------- batched attention GEMM: 256x256 tile, 8 waves, BK=32 ----------------
// att[b][l][r] = (lv[l,b,:]·rv[r,b,:]) * lmask * rmask, bf16 hi/lo 3-pass MFMA.
__global__ __launch_bounds__(512, 2) void gemm_att(const float* __restrict__ lv,
                                                   const float* __restrict__ rv,
                                                   const int* __restrict__ llen,
                                                   const int* __restrict__ rlen,
                                                   float* __restrict__ att) {
  __shared__ unsigned short Ah[256][40];
  __shared__ unsigned short Al[256][40];
  __shared__ unsigned short Bh[256][40];
  __shared__ unsigned short Bl[256][40];

  // 256 blocks, 8 XCDs -> 32 contiguous wids per XCD = 8 whole batches per XCD.
  const int bid = blockIdx.x;
  const int wid = (bid & 7) * 32 + (bid >> 3);
  const int b  = wid >> 2;
  const int l0 = ((wid >> 1) & 1) * 256;
  const int r0 = (wid & 1) * 256;

  const int t = threadIdx.x;       // 0..511
  const int srow = t >> 1;         // 0..255
  const int half = t & 1;
  const int kq = half * 16;        // ushort col base in BK=32 chunk

  const float* Abase = lv + (size_t)(l0 + srow) * BD + b * DD + kq;
  const float* Bbase = rv + (size_t)(r0 + srow) * BD + b * DD + kq;

  float4 pa[4], pb[4];
#pragma unroll
  for (int q = 0; q < 4; ++q) {
    pa[q] = *(const float4*)(Abase + q * 4);
    pb[q] = *(const float4*)(Bbase + q * 4);
  }

  const int lane = t & 63;
  const int wv = t >> 6;           // 0..7
  const int wrow = wv >> 2;        // 0..1 -> 128-row l slice
  const int wcol = wv & 3;         // 0..3 -> 64-col r slice
  const int fr = lane & 15;
  const int kh = lane >> 4;        // 0..3

  f32x4 acc[8][4];
#pragma unroll
  for (int i = 0; i < 8; ++i)
#pragma unroll
    for (int j = 0; j < 4; ++j) acc[i][j] = (f32x4){0.f, 0.f, 0.f, 0.f};

  for (int it = 0; it < 16; ++it) {
    __syncthreads();   // previous MFMA reads done
#pragma unroll
    for (int q = 0; q < 4; ++q) {
      unsigned h01, l01, h23, l23;
      split2(pa[q].x, pa[q].y, h01, l01);
      split2(pa[q].z, pa[q].w, h23, l23);
      *(uint2*)&Ah[srow][kq + q * 4] = make_uint2(h01, h23);
      *(uint2*)&Al[srow][kq + q * 4] = make_uint2(l01, l23);
      split2(pb[q].x, pb[q].y, h01, l01);
      split2(pb[q].z, pb[q].w, h23, l23);
      *(uint2*)&Bh[srow][kq + q * 4] = make_uint2(h01, h23);
      *(uint2*)&Bl[srow][kq + q * 4] = make_uint2(l01, l23);
    }
    if (it < 15) {
      const float* An = Abase + (it + 1) * 32;
      const float* Bn = Bbase + (it + 1) * 32;
#pragma unroll
      for (int q = 0; q < 4; ++q) {
        pa[q] = *(const float4*)(An + q * 4);
        pb[q] = *(const float4*)(Bn + q * 4);
      }
    }
    __syncthreads();   // LDS writes visible

    bf16x8 bh[4], bl[4];
#pragma unroll
    for (int j = 0; j < 4; ++j) {
      bh[j] = *(const bf16x8*)&Bh[wcol * 64 + j * 16 + fr][kh * 8];
      bl[j] = *(const bf16x8*)&Bl[wcol * 64 + j * 16 + fr][kh * 8];
    }
#pragma unroll
    for (int i = 0; i < 8; ++i) {
      bf16x8 ah = *(const bf16x8*)&Ah[wrow * 128 + i * 16 + fr][kh * 8];
      bf16x8 al = *(const bf16x8*)&Al[wrow * 128 + i * 16 + fr][kh * 8];
#pragma unroll
      for (int j = 0; j < 4; ++j) {
        acc[i][j] = __builtin_amdgcn_mfma_f32_16x16x32_bf16(ah, bh[j], acc[i][j], 0, 0, 0);
        acc[i][j] = __builtin_amdgcn_mfma_f32_16x16x32_bf16(ah, bl[j], acc[i][j], 0, 0, 0);
        acc[i][j] = __builtin_amdgcn_mfma_f32_16x16x32_bf16(al, bh[j], acc[i][j], 0, 0, 0);
      }
    }
  }

  const int ll_ = llen[b], rl_ = rlen[b];
#pragma unroll
  for (int i = 0; i < 8; ++i) {
#pragma unroll
    for (int q = 0; q < 4; ++q) {
      int l = l0 + wrow * 128 + i * 16 + kh * 4 + q;
      float lm = (l < ll_) ? 1.f : 0.f;
      float* orow = att + ((size_t)b * LL + l) * RR + r0 + wcol * 64;
#pragma unroll
      for (int j = 0; j < 4; ++j) {
        int r = r0 + wcol * 64 + j * 16 + fr;
        float m = (r < rl_) ? lm : 0.f;
        orow[j * 16 + fr] = acc[i][j][q] * m;
      }
    }
  }
}

// ---------------- wave reduce helpers ----------------
__device__ __forceinline__ float wmaxf(float v) {
#pragma unroll
  for (int m = 32; m; m >>= 1) v = fmaxf(v, __shfl_xor(v, m, 64));
  return v;
}
__device__ __forceinline__ float wsumf(float v) {
#pragma unroll
  for (int m = 32; m; m >>= 1) v += __shfl_xor(v, m, 64);
  return v;
}

// ---------------- l-side stats ----------------
__global__ __launch_bounds__(256) void stats_rows(const float* __restrict__ att,
    const int* __restrict__ llen, const int* __restrict__ rlen,
    float* __restrict__ w_out, float* __restrict__ an_out, int* __restrict__ idx_out) {
  const int lane = threadIdx.x & 63;
  const int row  = blockIdx.x * 4 + (threadIdx.x >> 6);  // row = b*512 + l
  const int b = row >> 9, l = row & 511;
  const int rl_ = rlen[b], ll_ = llen[b];
  const float* base = att + (size_t)row * RR;
  float s[8];
#pragma unroll
  for (int j = 0; j < 8; ++j) {
    int r = lane + 64*j;
    float v = base[r];
    s[j] = (r < rl_) ? v : v - 10.f;
  }
  float M = -1e30f;
#pragma unroll
  for (int j = 0; j < 8; ++j) M = fmaxf(M, s[j]);
  M = wmaxf(M);
  float e[8]; float z0 = 0.f, zv = 0.f;
  float bv = -1e30f; int bi = 0;
#pragma unroll
  for (int j = 0; j < 8; ++j) {
    int r = lane + 64*j;
    float ej = __expf(s[j] - M);
    z0 += ej;
    bool valid = (r < rl_);
    float evj = valid ? ej : 0.f;
    e[j] = evj;
    zv += evj;
    if (valid && evj > bv) { bv = evj; bi = r; }
  }
  z0 = wsumf(z0); zv = wsumf(zv);
  const float S = zv / z0;
  const float inv = 1.f / (S + 1e-13f);
  const float c = inv / z0;
  float q2 = 0.f;
#pragma unroll
  for (int j = 0; j < 8; ++j) { float q = e[j] * c; q2 += q * q; }
  q2 = wsumf(q2);
#pragma unroll
  for (int m = 32; m; m >>= 1) {
    float ov = __shfl_xor(bv, m, 64);
    int   oi = __shfl_xor(bi, m, 64);
    if (ov > bv || (ov == bv && oi < bi)) { bv = ov; bi = oi; }
  }
  if (lane == 0) {
    float rlf = (float)rl_;
    float sumq = S * inv;
    float mean = sumq / rlf;
    float var  = q2 / rlf - mean * mean;
    float wv   = var / fmaxf(mean, 0.001f);
    float qmax = bv * c;
    float an   = qmax / fmaxf(qmax, 0.001f);
    w_out[row]  = wv;
    an_out[row] = an;
    idx_out[row] = (l < ll_) ? bi : 0;
  }
}

// ---------------- r-side stats ----------------
__global__ __launch_bounds__(256) void stats_cols(const float* __restrict__ att,
    const int* __restrict__ llen, const int* __restrict__ rlen,
    float* __restrict__ w_out, float* __restrict__ an_out, int* __restrict__ idx_out) {
  __shared__ float mM[4][64], mZ[4][64], mZv[4][64], mQ[4][64], mB[4][64];
  __shared__ int   mI[4][64];
  const int b  = blockIdx.x >> 3;
  const int r0 = (blockIdx.x & 7) * 64;
  const int t  = threadIdx.x;
  const int cl = t & 63;
  const int part = t >> 6;
  const int col = r0 + cl;
  const int ll_ = llen[b], rl_ = rlen[b];
  const float* base = att + ((size_t)b * LL) * RR + col;
  float M = -1e30f, Z = 0.f, Zv = 0.f, Q = 0.f, bS = -1e30f;
  int bI = 0;
  const int l0 = part * 128;
  for (int li = 0; li < 128; ++li) {
    int l = l0 + li;
    float v = base[(size_t)l * RR];
    bool lmv = (l < ll_);
    float s = lmv ? v : v - 10.f;
    if (s > M) {
      float sc = __expf(M - s);
      Z *= sc; Zv *= sc; Q *= sc * sc;
      M = s;
    }
    float ej = __expf(s - M);
    Z += ej;
    if (lmv) {
      Zv += ej; Q += ej * ej;
      if (s > bS) { bS = s; bI = l; }
    }
  }
  mM[part][cl] = M; mZ[part][cl] = Z; mZv[part][cl] = Zv;
  mQ[part][cl] = Q; mB[part][cl] = bS; mI[part][cl] = bI;
  __syncthreads();
  if (t < 64) {
    float M0 = mM[0][t], Z0 = mZ[0][t], Zv0 = mZv[0][t], Q0 = mQ[0][t], bS0 = mB[0][t];
    int bI0 = mI[0][t];
#pragma unroll
    for (int p = 1; p < 4; ++p) {
      float M1 = mM[p][t], Z1 = mZ[p][t], Zv1 = mZv[p][t], Q1 = mQ[p][t], bS1 = mB[p][t];
      int bI1 = mI[p][t];
      float Mn = fmaxf(M0, M1);
      float c0 = __expf(M0 - Mn), c1 = __expf(M1 - Mn);
      Z0  = Z0 * c0 + Z1 * c1;
      Zv0 = Zv0 * c0 + Zv1 * c1;
      Q0  = Q0 * c0 * c0 + Q1 * c1 * c1;
      M0 = Mn;
      if (bS1 > bS0) { bS0 = bS1; bI0 = bI1; }
    }
    const float S = Zv0 / Z0;
    const float inv = 1.f / (S + 1e-13f);
    float llf = (float)ll_;
    float sumq = S * inv;
    float mean = sumq / llf;
    float sumq2 = Q0 / (Z0 * Z0) * inv * inv;
    float var = sumq2 / llf - mean * mean;
    float wv = var / fmaxf(mean, 0.001f);
    float qmax = __expf(bS0 - M0) / Z0 * inv;
    float an = qmax / fmaxf(qmax, 0.001f);
    int c_ = r0 + t;
    w_out[b * RR + c_]  = wv;
    an_out[b * RR + c_] = an;
    idx_out[b * RR + c_] = (c_ < rl_) ? bI0 : 0;
  }
}

// ---------------- prep: Wconv [100][512] -> bf16 hi/lo [112][512] (f-major, zero-padded) ------
__global__ void prep_w(const float* __restrict__ Wconv,
                       unsigned short* __restrict__ Whg, unsigned short* __restrict__ Wlg) {
  int i = blockIdx.x * 256 + threadIdx.x;
  if (i < FP * DD) {
    int f = i >> 9;
    float w = (f < FC) ? Wconv[i] : 0.f;
    unsigned short h = bf16rne(w);
    unsigned short l = bf16rne(w - bf16tof(h));
    Whg[i] = h; Wlg[i] = l;
  }
}

// ---------------- conv + relu + masked maxpool via bf16 hi/lo MFMA ----------------
__global__ __launch_bounds__(256) void conv_pool_mfma(const float* __restrict__ lv,
    const float* __restrict__ rv,
    const float* __restrict__ lwv, const float* __restrict__ lan, const int* __restrict__ lidx,
    const float* __restrict__ rwv, const float* __restrict__ ran, const int* __restrict__ ridx,
    const int* __restrict__ llen, const int* __restrict__ rlen,
    const unsigned short* __restrict__ Whg, const unsigned short* __restrict__ Wlg,
    const float* __restrict__ bconv, float* __restrict__ feat) {
  __shared__ unsigned short Ah[128][40];
  __shared__ unsigned short Al[128][40];
  __shared__ unsigned short Wh[FP][40];
  __shared__ unsigned short Wl[FP][40];
  __shared__ float pool[4][FP];
  __shared__ float ppw[128], ppa[128];
  __shared__ int   ppi[128], ppv[128];

  const int bid = blockIdx.x;
  const int wid = (bid & 7) * 64 + (bid >> 3);
  const int side = wid >> 8;
  const int b    = (wid >> 2) & 63;
  const int s0   = (wid & 3) * 128;

  const int t = threadIdx.x;
  const float* x; const float* y; const float* wb; const float* ab; const int* ib; int plen;
  if (side == 0) { x = lv; y = rv; wb = lwv; ab = lan; ib = lidx; plen = llen[b]; }
  else           { x = rv; y = lv; wb = rwv; ab = ran; ib = ridx; plen = rlen[b]; }

  if (t < 128) {
    int pos = s0 + t;
    ppw[t] = wb[b * 512 + pos];
    ppa[t] = ab[b * 512 + pos];
    ppi[t] = ib[b * 512 + pos];
    ppv[t] = (pos < plen) ? 1 : 0;
  }
  __syncthreads();

  const int pos  = t >> 1;
  const int half = t & 1;
  const float w_ = ppw[pos];
  const float a_ = ppa[pos];
  const int   yi = ppi[pos];
  const float* xp = x + (size_t)(s0 + pos) * BD + b * DD + half * 16;
  const float* yp = y + (size_t)yi * BD + b * DD + half * 16;

  float4 xv[4], yv[4];
#pragma unroll
  for (int q = 0; q < 4; ++q) {
    xv[q] = *(const float4*)(xp + q * 4);
    yv[q] = *(const float4*)(yp + q * 4);
  }

  const int lane = t & 63;
  const int wvi = t >> 6;        // wave 0..3
  const int m0 = wvi * 32;
  const int fr = lane & 15;
  const int kh = lane >> 4;

  f32x4 acc[2][7];
#pragma unroll
  for (int i = 0; i < 2; ++i)
#pragma unroll
    for (int j = 0; j < 7; ++j) acc[i][j] = (f32x4){0.f, 0.f, 0.f, 0.f};

  for (int it = 0; it < 16; ++it) {
    const int k0 = it * 32;
    __syncthreads();
#pragma unroll
    for (int q = 0; q < 2; ++q) {
      float d0 = w_ * fabsf(xv[2*q].x   - a_ * yv[2*q].x);
      float d1 = w_ * fabsf(xv[2*q].y   - a_ * yv[2*q].y);
      float d2 = w_ * fabsf(xv[2*q].z   - a_ * yv[2*q].z);
      float d3 = w_ * fabsf(xv[2*q].w   - a_ * yv[2*q].w);
      float d4 = w_ * fabsf(xv[2*q+1].x - a_ * yv[2*q+1].x);
      float d5 = w_ * fabsf(xv[2*q+1].y - a_ * yv[2*q+1].y);
      float d6 = w_ * fabsf(xv[2*q+1].z - a_ * yv[2*q+1].z);
      float d7 = w_ * fabsf(xv[2*q+1].w - a_ * yv[2*q+1].w);
      unsigned h01, l01, h23, l23, h45, l45, h67, l67;
      split2(d0, d1, h01, l01);
      split2(d2, d3, h23, l23);
      split2(d4, d5, h45, l45);
      split2(d6, d7, h67, l67);
      *(uint4*)&Ah[pos][half * 16 + q * 8] = make_uint4(h01, h23, h45, h67);
      *(uint4*)&Al[pos][half * 16 + q * 8] = make_uint4(l01, l23, l45, l67);
    }
#pragma unroll
    for (int rep = 0; rep < 2; ++rep) {
      int idx = t + rep * 256;
      if (idx < FP * 4) {
        int f = idx >> 2, q = idx & 3;
        *(ulonglong2*)&Wh[f][q * 8] = *(const ulonglong2*)&Whg[f * DD + k0 + q * 8];
        *(ulonglong2*)&Wl[f][q * 8] = *(const ulonglong2*)&Wlg[f * DD + k0 + q * 8];
      }
    }
    if (it < 15) {
      const float* xn = xp + k0 + 32;
      const float* yn = yp + k0 + 32;
#pragma unroll
      for (int q = 0; q < 4; ++q) {
        xv[q] = *(const float4*)(xn + q * 4);
        yv[q] = *(const float4*)(yn + q * 4);
      }
    }
    __syncthreads();

    bf16x8 ah[2], al[2];
#pragma unroll
    for (int i = 0; i < 2; ++i) {
      ah[i] = *(const bf16x8*)&Ah[m0 + i * 16 + fr][kh * 8];
      al[i] = *(const bf16x8*)&Al[m0 + i * 16 + fr][kh * 8];
    }
#pragma unroll
    for (int j = 0; j < 7; ++j) {
      bf16x8 bh = *(const bf16x8*)&Wh[j * 16 + fr][kh * 8];
      bf16x8 bl = *(const bf16x8*)&Wl[j * 16 + fr][kh * 8];
#pragma unroll
      for (int i = 0; i < 2; ++i) {
        acc[i][j] = __builtin_amdgcn_mfma_f32_16x16x32_bf16(ah[i], bh, acc[i][j], 0, 0, 0);
        acc[i][j] = __builtin_amdgcn_mfma_f32_16x16x32_bf16(ah[i], bl, acc[i][j], 0, 0, 0);
        acc[i][j] = __builtin_amdgcn_mfma_f32_16x16x32_bf16(al[i], bh, acc[i][j], 0, 0, 0);
      }
    }
  }

  // epilogue: bias + relu + validity + maxpool
#pragma unroll
  for (int j = 0; j < 7; ++j) {
    int f = j * 16 + fr;
    float bcv = (f < FC) ? bconv[f] : 0.f;
    float vmax = -1e30f;
#pragma unroll
    for (int i = 0; i < 2; ++i) {
#pragma unroll
      for (int q = 0; q < 4; ++q) {
        int sl = m0 + i * 16 + kh * 4 + q;
        if (ppv[sl]) vmax = fmaxf(vmax, fmaxf(acc[i][j][q] + bcv, 0.f));
      }
    }
    vmax = fmaxf(vmax, __shfl_xor(vmax, 16, 64));
    vmax = fmaxf(vmax, __shfl_xor(vmax, 32, 64));
    if (lane < 16) pool[wvi][f] = vmax;
  }
  __syncthreads();
  if (t < FC) {
    float v = fmaxf(fmaxf(pool[0][t], pool[1][t]), fmaxf(pool[2][t], pool[3][t]));
    if (v > -1e29f) atomicMax((int*)&feat[b * 200 + side * FC + t], __float_as_int(v));
  }
}

// ---------------- final dense [B,200] x [200,60] + relu ----------------
__global__ void dense_out(const float* __restrict__ feat, const float* __restrict__ Wd,
                          const float* __restrict__ bd, float* __restrict__ out) {
  int b = blockIdx.x, h = threadIdx.x;
  if (h < HH) {
    float s = bd[h];
    const float* fb = feat + b * 200;
    const float* wr = Wd + h * 200;
    for (int k = 0; k < 200; ++k) s += fb[k] * wr[k];
    out[b * HH + h] = fmaxf(s, 0.f);
  }
}

extern "C" void kernel_launch(void* const* d_in, const int* in_sizes, int n_in,
                              void* d_out, int out_size, void* d_ws, size_t ws_size,
                              hipStream_t stream) {
  (void)in_sizes; (void)n_in; (void)out_size; (void)ws_size;
  const int*   llen  = (const int*)d_in[0];
  const float* lv    = (const float*)d_in[1];
  const int*   rlen  = (const int*)d_in[2];
  const float* rv    = (const float*)d_in[3];
  const float* Wconv = (const float*)d_in[4];
  const float* bconv = (const float*)d_in[5];
  const float* Wd    = (const float*)d_in[6];
  const float* bd    = (const float*)d_in[7];
  float* out = (float*)d_out;
  char* ws = (char*)d_ws;
  size_t off = 0;
  float* att = (float*)(ws + off); off += (size_t)BB * LL * RR * 4;  // 64 MiB
  unsigned short* Whg = (unsigned short*)(ws + off); off += (size_t)FP * DD * 2;
  unsigned short* Wlg = (unsigned short*)(ws + off); off += (size_t)FP * DD * 2;
  float* lwv = (float*)(ws + off); off += (size_t)BB * LL * 4;
  float* lan = (float*)(ws + off); off += (size_t)BB * LL * 4;
  int*   lidx= (int*)  (ws + off); off += (size_t)BB * LL * 4;
  float* rwv = (float*)(ws + off); off += (size_t)BB * RR * 4;
  float* ran = (float*)(ws + off); off += (size_t)BB * RR * 4;
  int*   ridx= (int*)  (ws + off); off += (size_t)BB * RR * 4;
  float* feat= (float*)(ws + off); off += (size_t)BB * 200 * 4;

  hipMemsetAsync(feat, 0, BB * 200 * 4, stream);
  prep_w<<<(FP * DD + 255) / 256, 256, 0, stream>>>(Wconv, Whg, Wlg);
  gemm_att<<<dim3(256), 512, 0, stream>>>(lv, rv, llen, rlen, att);
  stats_rows<<<BB * LL / 4, 256, 0, stream>>>(att, llen, rlen, lwv, lan, lidx);
  stats_cols<<<BB * 8, 256, 0, stream>>>(att, llen, rlen, rwv, ran, ridx);
  conv_pool_mfma<<<dim3(512), 256, 0, stream>>>(lv, rv, lwv, lan, lidx,
                                                rwv, ran, ridx, llen, rlen,
                                                Whg, Wlg, bconv, feat);
  dense_out<<<BB, 64, 0, stream>>>(feat, Wd, bd, out);
}

// Round 6
// 135.659 us; speedup vs baseline: 3.6819x; 1.2657x over previous
//
#include <hip/hip_runtime.h>
#include <math.h>

#define BB 64
#define LL 512
#define RR 512
#define DD 512
#define FC 100
#define FP 112
#define HH 60
#define BD (BB*DD)

typedef __attribute__((ext_vector_type(8))) short bf16x8;
typedef __attribute__((ext_vector_type(4))) float f32x4;

__device__ __forceinline__ unsigned short bf16rne(float x) {
  unsigned u = __float_as_uint(x);
  return (unsigned short)((u + 0x7fffu + ((u >> 16) & 1u)) >> 16);
}
__device__ __forceinline__ float bf16tof(unsigned short h) {
  return __uint_as_float((unsigned)h << 16);
}

// Truncating hi/lo bf16 split of 2 floats, packed via v_perm_b32.
__device__ __forceinline__ void split2(float x0, float x1, unsigned& h2, unsigned& l2) {
  unsigned u0 = __float_as_uint(x0), u1 = __float_as_uint(x1);
  h2 = __builtin_amdgcn_perm(u1, u0, 0x07060302u);
  float r0 = x0 - __uint_as_float(u0 & 0xffff0000u);
  float r1 = x1 - __uint_as_float(u1 & 0xffff0000u);
  l2 = __builtin_amdgcn_perm(__float_as_uint(r1), __float_as_uint(r0), 0x07060302u);
}

// ---------------- fused attention GEMM + per-block softmax-stat partials ----------------
// Computes raw scores for a 256x256 tile via bf16 hi/lo 3-pass MFMA, then reduces
// row-wise (att_l over r) and col-wise (att_r over l) partials {M,z0,zv,q2,bS,bI}
// and writes them to lpart/rpart. att is never materialized.
__global__ __launch_bounds__(512, 2) void gemm_att(const float* __restrict__ lv,
                                                   const float* __restrict__ rv,
                                                   const int* __restrict__ llen,
                                                   const int* __restrict__ rlen,
                                                   float* __restrict__ lpart,
                                                   float* __restrict__ rpart) {
  __shared__ unsigned short Ah[256][40];
  __shared__ unsigned short Al[256][40];
  __shared__ unsigned short Bh[256][40];
  __shared__ unsigned short Bl[256][40];

  // 256 blocks, 8 XCDs -> 32 contiguous wids per XCD = 8 whole batches per XCD.
  const int bid = blockIdx.x;
  const int wid = (bid & 7) * 32 + (bid >> 3);
  const int b  = wid >> 2;
  const int l0 = ((wid >> 1) & 1) * 256;
  const int r0 = (wid & 1) * 256;

  const int t = threadIdx.x;       // 0..511
  const int srow = t >> 1;         // 0..255
  const int half = t & 1;
  const int kq = half * 16;        // ushort col base in BK=32 chunk

  const float* Abase = lv + (size_t)(l0 + srow) * BD + b * DD + kq;
  const float* Bbase = rv + (size_t)(r0 + srow) * BD + b * DD + kq;

  float4 pa[4], pb[4];
#pragma unroll
  for (int q = 0; q < 4; ++q) {
    pa[q] = *(const float4*)(Abase + q * 4);
    pb[q] = *(const float4*)(Bbase + q * 4);
  }

  const int lane = t & 63;
  const int wv = t >> 6;           // 0..7
  const int wrow = wv >> 2;        // 0..1 -> 128-row l slice
  const int wcol = wv & 3;         // 0..3 -> 64-col r slice
  const int fr = lane & 15;
  const int kh = lane >> 4;        // 0..3

  f32x4 acc[8][4];
#pragma unroll
  for (int i = 0; i < 8; ++i)
#pragma unroll
    for (int j = 0; j < 4; ++j) acc[i][j] = (f32x4){0.f, 0.f, 0.f, 0.f};

  for (int it = 0; it < 16; ++it) {
    __syncthreads();   // previous MFMA reads done
#pragma unroll
    for (int q = 0; q < 4; ++q) {
      unsigned h01, l01, h23, l23;
      split2(pa[q].x, pa[q].y, h01, l01);
      split2(pa[q].z, pa[q].w, h23, l23);
      *(uint2*)&Ah[srow][kq + q * 4] = make_uint2(h01, h23);
      *(uint2*)&Al[srow][kq + q * 4] = make_uint2(l01, l23);
      split2(pb[q].x, pb[q].y, h01, l01);
      split2(pb[q].z, pb[q].w, h23, l23);
      *(uint2*)&Bh[srow][kq + q * 4] = make_uint2(h01, h23);
      *(uint2*)&Bl[srow][kq + q * 4] = make_uint2(l01, l23);
    }
    if (it < 15) {
      const float* An = Abase + (it + 1) * 32;
      const float* Bn = Bbase + (it + 1) * 32;
#pragma unroll
      for (int q = 0; q < 4; ++q) {
        pa[q] = *(const float4*)(An + q * 4);
        pb[q] = *(const float4*)(Bn + q * 4);
      }
    }
    __syncthreads();   // LDS writes visible

    bf16x8 bh[4], bl[4];
#pragma unroll
    for (int j = 0; j < 4; ++j) {
      bh[j] = *(const bf16x8*)&Bh[wcol * 64 + j * 16 + fr][kh * 8];
      bl[j] = *(const bf16x8*)&Bl[wcol * 64 + j * 16 + fr][kh * 8];
    }
#pragma unroll
    for (int i = 0; i < 8; ++i) {
      bf16x8 ah = *(const bf16x8*)&Ah[wrow * 128 + i * 16 + fr][kh * 8];
      bf16x8 al = *(const bf16x8*)&Al[wrow * 128 + i * 16 + fr][kh * 8];
#pragma unroll
      for (int j = 0; j < 4; ++j) {
        acc[i][j] = __builtin_amdgcn_mfma_f32_16x16x32_bf16(ah, bh[j], acc[i][j], 0, 0, 0);
        acc[i][j] = __builtin_amdgcn_mfma_f32_16x16x32_bf16(ah, bl[j], acc[i][j], 0, 0, 0);
        acc[i][j] = __builtin_amdgcn_mfma_f32_16x16x32_bf16(al, bh[j], acc[i][j], 0, 0, 0);
      }
    }
  }

  // ================= fused stats epilogue =================
  const int ll_ = llen[b], rl_ = rlen[b];
  __syncthreads();                       // all waves done with staging LDS
  float* rowsc = (float*)&Ah[0][0];      // [4 wcol][256 row][6]  (24 KB, aliases Ah/Al)
  float* colsc = (float*)&Bh[0][0];      // [2 wrow][256 col][6]  (12 KB, aliases Bh)

  // ---- row-side (att_l: softmax over r). s = !vr ? -10 : (vl ? raw : 0) ----
#pragma unroll
  for (int i = 0; i < 8; ++i) {
#pragma unroll
    for (int q = 0; q < 4; ++q) {
      const int lrow = wrow * 128 + i * 16 + kh * 4 + q;   // 0..255 in tile
      const bool vl = (l0 + lrow) < ll_;
      float s[4];
      float M = -1e30f, bS = -1e30f; int bI = 0;
#pragma unroll
      for (int j = 0; j < 4; ++j) {
        int r = r0 + wcol * 64 + j * 16 + fr;
        bool vr = r < rl_;
        float raw = acc[i][j][q];
        s[j] = !vr ? -10.f : (vl ? raw : 0.f);
        M = fmaxf(M, s[j]);
        if (vr && s[j] > bS) { bS = s[j]; bI = r; }   // j ascending -> r ascending
      }
#pragma unroll
      for (int m = 1; m < 16; m <<= 1) M = fmaxf(M, __shfl_xor(M, m, 64));
      float z0 = 0.f, zv = 0.f, q2 = 0.f;
#pragma unroll
      for (int j = 0; j < 4; ++j) {
        float e = __expf(s[j] - M);
        z0 += e;
        int r = r0 + wcol * 64 + j * 16 + fr;
        if (r < rl_) { zv += e; q2 += e * e; }
      }
#pragma unroll
      for (int m = 1; m < 16; m <<= 1) {
        z0 += __shfl_xor(z0, m, 64);
        zv += __shfl_xor(zv, m, 64);
        q2 += __shfl_xor(q2, m, 64);
        float oS = __shfl_xor(bS, m, 64);
        int   oI = __shfl_xor(bI, m, 64);
        if (oS > bS || (oS == bS && oI < bI)) { bS = oS; bI = oI; }
      }
      if (fr == 0) {
        float* p = rowsc + (wcol * 256 + lrow) * 6;
        p[0] = M; p[1] = z0; p[2] = zv; p[3] = q2; p[4] = bS; p[5] = __int_as_float(bI);
      }
    }
  }

  // ---- col-side (att_r: softmax over l). s = !vl ? -10 : (vr ? raw : 0) ----
#pragma unroll
  for (int j = 0; j < 4; ++j) {
    const int ccol = wcol * 64 + j * 16 + fr;              // 0..255 in tile
    const bool vr = (r0 + ccol) < rl_;
    float M = -1e30f, bS = -1e30f; int bI = 0;
#pragma unroll
    for (int i = 0; i < 8; ++i)
#pragma unroll
      for (int q = 0; q < 4; ++q) {
        int lg = l0 + wrow * 128 + i * 16 + kh * 4 + q;
        bool vl = lg < ll_;
        float raw = acc[i][j][q];
        float sv = !vl ? -10.f : (vr ? raw : 0.f);
        M = fmaxf(M, sv);
        if (vl && sv > bS) { bS = sv; bI = lg; }          // (i,q) ascending -> l ascending
      }
    float z0 = 0.f, zv = 0.f, q2 = 0.f;
#pragma unroll
    for (int i = 0; i < 8; ++i)
#pragma unroll
      for (int q = 0; q < 4; ++q) {
        int lg = l0 + wrow * 128 + i * 16 + kh * 4 + q;
        bool vl = lg < ll_;
        float raw = acc[i][j][q];
        float sv = !vl ? -10.f : (vr ? raw : 0.f);
        float e = __expf(sv - M);
        z0 += e;
        if (vl) { zv += e; q2 += e * e; }
      }
#pragma unroll
    for (int m = 16; m < 64; m <<= 1) {                   // merge kh groups
      float oM = __shfl_xor(M, m, 64);
      float oz0 = __shfl_xor(z0, m, 64);
      float ozv = __shfl_xor(zv, m, 64);
      float oq2 = __shfl_xor(q2, m, 64);
      float oS = __shfl_xor(bS, m, 64);
      int   oI = __shfl_xor(bI, m, 64);
      float Mn = fmaxf(M, oM);
      float c0 = __expf(M - Mn), c1 = __expf(oM - Mn);
      z0 = z0 * c0 + oz0 * c1;
      zv = zv * c0 + ozv * c1;
      q2 = q2 * c0 * c0 + oq2 * c1 * c1;
      M = Mn;
      if (oS > bS || (oS == bS && oI < bI)) { bS = oS; bI = oI; }
    }
    if (kh == 0) {
      float* p = colsc + (wrow * 256 + ccol) * 6;
      p[0] = M; p[1] = z0; p[2] = zv; p[3] = q2; p[4] = bS; p[5] = __int_as_float(bI);
    }
  }

  __syncthreads();

  // ---- block merge + partial write ----
  if (t < 256) {
    const float* p = rowsc + t * 6;
    float M = p[0], z0 = p[1], zv = p[2], q2 = p[3], bS = p[4];
    int bI = __float_as_int(p[5]);
#pragma unroll
    for (int w2 = 1; w2 < 4; ++w2) {                      // ascending r slices
      const float* pp = rowsc + (w2 * 256 + t) * 6;
      float M1 = pp[0], z01 = pp[1], zv1 = pp[2], q21 = pp[3], bS1 = pp[4];
      int bI1 = __float_as_int(pp[5]);
      float Mn = fmaxf(M, M1);
      float c0 = __expf(M - Mn), c1 = __expf(M1 - Mn);
      z0 = z0 * c0 + z01 * c1;
      zv = zv * c0 + zv1 * c1;
      q2 = q2 * c0 * c0 + q21 * c1 * c1;
      M = Mn;
      if (bS1 > bS || (bS1 == bS && bI1 < bI)) { bS = bS1; bI = bI1; }
    }
    const int l = l0 + t;
    float* dst = lpart + (((size_t)(b * 512 + l)) * 2 + (r0 >> 8)) * 6;
    *(float2*)(dst + 0) = make_float2(M, z0);
    *(float2*)(dst + 2) = make_float2(zv, q2);
    *(float2*)(dst + 4) = make_float2(bS, __int_as_float(bI));
  } else {
    const int c = t - 256;
    const float* p = colsc + c * 6;
    float M = p[0], z0 = p[1], zv = p[2], q2 = p[3], bS = p[4];
    int bI = __float_as_int(p[5]);
    {
      const float* pp = colsc + (256 + c) * 6;            // wrow 1 = higher l
      float M1 = pp[0], z01 = pp[1], zv1 = pp[2], q21 = pp[3], bS1 = pp[4];
      int bI1 = __float_as_int(pp[5]);
      float Mn = fmaxf(M, M1);
      float c0 = __expf(M - Mn), c1 = __expf(M1 - Mn);
      z0 = z0 * c0 + z01 * c1;
      zv = zv * c0 + zv1 * c1;
      q2 = q2 * c0 * c0 + q21 * c1 * c1;
      M = Mn;
      if (bS1 > bS || (bS1 == bS && bI1 < bI)) { bS = bS1; bI = bI1; }
    }
    const int r = r0 + c;
    float* dst = rpart + (((size_t)(b * 512 + r)) * 2 + (l0 >> 8)) * 6;
    *(float2*)(dst + 0) = make_float2(M, z0);
    *(float2*)(dst + 2) = make_float2(zv, q2);
    *(float2*)(dst + 4) = make_float2(bS, __int_as_float(bI));
  }
}

// ---------------- merge 2 slice-partials per row/col -> final stats ----------------
__global__ __launch_bounds__(256) void stats_merge(const float* __restrict__ lpart,
    const float* __restrict__ rpart,
    const int* __restrict__ llen, const int* __restrict__ rlen,
    float* __restrict__ lwv, float* __restrict__ lan, int* __restrict__ lidx,
    float* __restrict__ rwv, float* __restrict__ ran, int* __restrict__ ridx) {
  const int gid = blockIdx.x * 256 + threadIdx.x;  // 0..65535
  const int side = gid >> 15;
  const int pos = gid & 32767;                     // b*512 + p
  const int b = pos >> 9, p = pos & 511;
  const float* part = (side ? rpart : lpart) + (size_t)pos * 12;
  float M = part[0], z0 = part[1], zv = part[2], q2 = part[3], bS = part[4];
  int bI = __float_as_int(part[5]);
  {
    float M1 = part[6], z01 = part[7], zv1 = part[8], q21 = part[9], bS1 = part[10];
    int bI1 = __float_as_int(part[11]);
    float Mn = fmaxf(M, M1);
    float c0 = __expf(M - Mn), c1 = __expf(M1 - Mn);
    z0 = z0 * c0 + z01 * c1;
    zv = zv * c0 + zv1 * c1;
    q2 = q2 * c0 * c0 + q21 * c1 * c1;
    M = Mn;
    if (bS1 > bS || (bS1 == bS && bI1 < bI)) { bS = bS1; bI = bI1; }
  }
  const int len = side ? llen[b] : rlen[b];   // att_l sums /rl ; att_r sums /ll
  const int own = side ? rlen[b] : llen[b];
  float S = zv / z0;
  float inv = 1.f / (S + 1e-13f);
  float sumq = S * inv;
  float mean = sumq / (float)len;
  float sumq2 = q2 / (z0 * z0) * inv * inv;
  float var = sumq2 / (float)len - mean * mean;
  float wv = var / fmaxf(mean, 0.001f);
  float qmax = __expf(bS - M) / z0 * inv;
  float an = qmax / fmaxf(qmax, 0.001f);
  int idx = (p < own) ? bI : 0;
  if (side == 0) { lwv[pos] = wv; lan[pos] = an; lidx[pos] = idx; }
  else           { rwv[pos] = wv; ran[pos] = an; ridx[pos] = idx; }
}

// ---------------- prep: Wconv [100][512] -> bf16 hi/lo [112][512] (f-major, zero-padded) ------
__global__ void prep_w(const float* __restrict__ Wconv,
                       unsigned short* __restrict__ Whg, unsigned short* __restrict__ Wlg) {
  int i = blockIdx.x * 256 + threadIdx.x;
  if (i < FP * DD) {
    int f = i >> 9;
    float w = (f < FC) ? Wconv[i] : 0.f;
    unsigned short h = bf16rne(w);
    unsigned short l = bf16rne(w - bf16tof(h));
    Whg[i] = h; Wlg[i] = l;
  }
}

// ---------------- conv + relu + masked maxpool via bf16 hi/lo MFMA ----------------
__global__ __launch_bounds__(256) void conv_pool_mfma(const float* __restrict__ lv,
    const float* __restrict__ rv,
    const float* __restrict__ lwv, const float* __restrict__ lan, const int* __restrict__ lidx,
    const float* __restrict__ rwv, const float* __restrict__ ran, const int* __restrict__ ridx,
    const int* __restrict__ llen, const int* __restrict__ rlen,
    const unsigned short* __restrict__ Whg, const unsigned short* __restrict__ Wlg,
    const float* __restrict__ bconv, float* __restrict__ feat) {
  __shared__ unsigned short Ah[128][40];
  __shared__ unsigned short Al[128][40];
  __shared__ unsigned short Wh[FP][40];
  __shared__ unsigned short Wl[FP][40];
  __shared__ float pool[4][FP];
  __shared__ float ppw[128], ppa[128];
  __shared__ int   ppi[128], ppv[128];

  const int bid = blockIdx.x;
  const int wid = (bid & 7) * 64 + (bid >> 3);
  const int side = wid >> 8;
  const int b    = (wid >> 2) & 63;
  const int s0   = (wid & 3) * 128;

  const int t = threadIdx.x;
  const float* x; const float* y; const float* wb; const float* ab; const int* ib; int plen;
  if (side == 0) { x = lv; y = rv; wb = lwv; ab = lan; ib = lidx; plen = llen[b]; }
  else           { x = rv; y = lv; wb = rwv; ab = ran; ib = ridx; plen = rlen[b]; }

  if (t < 128) {
    int pos = s0 + t;
    ppw[t] = wb[b * 512 + pos];
    ppa[t] = ab[b * 512 + pos];
    ppi[t] = ib[b * 512 + pos];
    ppv[t] = (pos < plen) ? 1 : 0;
  }
  __syncthreads();

  const int pos  = t >> 1;
  const int half = t & 1;
  const float w_ = ppw[pos];
  const float a_ = ppa[pos];
  const int   yi = ppi[pos];
  const float* xp = x + (size_t)(s0 + pos) * BD + b * DD + half * 16;
  const float* yp = y + (size_t)yi * BD + b * DD + half * 16;

  float4 xv[4], yv[4];
#pragma unroll
  for (int q = 0; q < 4; ++q) {
    xv[q] = *(const float4*)(xp + q * 4);
    yv[q] = *(const float4*)(yp + q * 4);
  }

  const int lane = t & 63;
  const int wvi = t >> 6;        // wave 0..3
  const int m0 = wvi * 32;
  const int fr = lane & 15;
  const int kh = lane >> 4;

  f32x4 acc[2][7];
#pragma unroll
  for (int i = 0; i < 2; ++i)
#pragma unroll
    for (int j = 0; j < 7; ++j) acc[i][j] = (f32x4){0.f, 0.f, 0.f, 0.f};

  for (int it = 0; it < 16; ++it) {
    const int k0 = it * 32;
    __syncthreads();
#pragma unroll
    for (int q = 0; q < 2; ++q) {
      float d0 = w_ * fabsf(xv[2*q].x   - a_ * yv[2*q].x);
      float d1 = w_ * fabsf(xv[2*q].y   - a_ * yv[2*q].y);
      float d2 = w_ * fabsf(xv[2*q].z   - a_ * yv[2*q].z);
      float d3 = w_ * fabsf(xv[2*q].w   - a_ * yv[2*q].w);
      float d4 = w_ * fabsf(xv[2*q+1].x - a_ * yv[2*q+1].x);
      float d5 = w_ * fabsf(xv[2*q+1].y - a_ * yv[2*q+1].y);
      float d6 = w_ * fabsf(xv[2*q+1].z - a_ * yv[2*q+1].z);
      float d7 = w_ * fabsf(xv[2*q+1].w - a_ * yv[2*q+1].w);
      unsigned h01, l01, h23, l23, h45, l45, h67, l67;
      split2(d0, d1, h01, l01);
      split2(d2, d3, h23, l23);
      split2(d4, d5, h45, l45);
      split2(d6, d7, h67, l67);
      *(uint4*)&Ah[pos][half * 16 + q * 8] = make_uint4(h01, h23, h45, h67);
      *(uint4*)&Al[pos][half * 16 + q * 8] = make_uint4(l01, l23, l45, l67);
    }
#pragma unroll
    for (int rep = 0; rep < 2; ++rep) {
      int idx = t + rep * 256;
      if (idx < FP * 4) {
        int f = idx >> 2, q = idx & 3;
        *(ulonglong2*)&Wh[f][q * 8] = *(const ulonglong2*)&Whg[f * DD + k0 + q * 8];
        *(ulonglong2*)&Wl[f][q * 8] = *(const ulonglong2*)&Wlg[f * DD + k0 + q * 8];
      }
    }
    if (it < 15) {
      const float* xn = xp + k0 + 32;
      const float* yn = yp + k0 + 32;
#pragma unroll
      for (int q = 0; q < 4; ++q) {
        xv[q] = *(const float4*)(xn + q * 4);
        yv[q] = *(const float4*)(yn + q * 4);
      }
    }
    __syncthreads();

    bf16x8 ah[2], al[2];
#pragma unroll
    for (int i = 0; i < 2; ++i) {
      ah[i] = *(const bf16x8*)&Ah[m0 + i * 16 + fr][kh * 8];
      al[i] = *(const bf16x8*)&Al[m0 + i * 16 + fr][kh * 8];
    }
#pragma unroll
    for (int j = 0; j < 7; ++j) {
      bf16x8 bh = *(const bf16x8*)&Wh[j * 16 + fr][kh * 8];
      bf16x8 bl = *(const bf16x8*)&Wl[j * 16 + fr][kh * 8];
#pragma unroll
      for (int i = 0; i < 2; ++i) {
        acc[i][j] = __builtin_amdgcn_mfma_f32_16x16x32_bf16(ah[i], bh, acc[i][j], 0, 0, 0);
        acc[i][j] = __builtin_amdgcn_mfma_f32_16x16x32_bf16(ah[i], bl, acc[i][j], 0, 0, 0);
        acc[i][j] = __builtin_amdgcn_mfma_f32_16x16x32_bf16(al[i], bh, acc[i][j], 0, 0, 0);
      }
    }
  }

  // epilogue: bias + relu + validity + maxpool
#pragma unroll
  for (int j = 0; j < 7; ++j) {
    int f = j * 16 + fr;
    float bcv = (f < FC) ? bconv[f] : 0.f;
    float vmax = -1e30f;
#pragma unroll
    for (int i = 0; i < 2; ++i) {
#pragma unroll
      for (int q = 0; q < 4; ++q) {
        int sl = m0 + i * 16 + kh * 4 + q;
        if (ppv[sl]) vmax = fmaxf(vmax, fmaxf(acc[i][j][q] + bcv, 0.f));
      }
    }
    vmax = fmaxf(vmax, __shfl_xor(vmax, 16, 64));
    vmax = fmaxf(vmax, __shfl_xor(vmax, 32, 64));
    if (lane < 16) pool[wvi][f] = vmax;
  }
  __syncthreads();
  if (t < FC) {
    float v = fmaxf(fmaxf(pool[0][t], pool[1][t]), fmaxf(pool[2][t], pool[3][t]));
    if (v > -1e29f) atomicMax((int*)&feat[b * 200 + side * FC + t], __float_as_int(v));
  }
}

// ---------------- final dense [B,200] x [200,60] + relu ----------------
__global__ void dense_out(const float* __restrict__ feat, const float* __restrict__ Wd,
                          const float* __restrict__ bd, float* __restrict__ out) {
  int b = blockIdx.x, h = threadIdx.x;
  if (h < HH) {
    float s = bd[h];
    const float* fb = feat + b * 200;
    const float* wr = Wd + h * 200;
    for (int k = 0; k < 200; ++k) s += fb[k] * wr[k];
    out[b * HH + h] = fmaxf(s, 0.f);
  }
}

extern "C" void kernel_launch(void* const* d_in, const int* in_sizes, int n_in,
                              void* d_out, int out_size, void* d_ws, size_t ws_size,
                              hipStream_t stream) {
  (void)in_sizes; (void)n_in; (void)out_size; (void)ws_size;
  const int*   llen  = (const int*)d_in[0];
  const float* lv    = (const float*)d_in[1];
  const int*   rlen  = (const int*)d_in[2];
  const float* rv    = (const float*)d_in[3];
  const float* Wconv = (const float*)d_in[4];
  const float* bconv = (const float*)d_in[5];
  const float* Wd    = (const float*)d_in[6];
  const float* bd    = (const float*)d_in[7];
  float* out = (float*)d_out;
  char* ws = (char*)d_ws;
  size_t off = 0;
  unsigned short* Whg = (unsigned short*)(ws + off); off += (size_t)FP * DD * 2;
  unsigned short* Wlg = (unsigned short*)(ws + off); off += (size_t)FP * DD * 2;
  float* lpart = (float*)(ws + off); off += (size_t)BB * LL * 2 * 6 * 4;   // 1.5 MiB
  float* rpart = (float*)(ws + off); off += (size_t)BB * RR * 2 * 6 * 4;   // 1.5 MiB
  float* lwv = (float*)(ws + off); off += (size_t)BB * LL * 4;
  float* lan = (float*)(ws + off); off += (size_t)BB * LL * 4;
  int*   lidx= (int*)  (ws + off); off += (size_t)BB * LL * 4;
  float* rwv = (float*)(ws + off); off += (size_t)BB * RR * 4;
  float* ran = (float*)(ws + off); off += (size_t)BB * RR * 4;
  int*   ridx= (int*)  (ws + off); off += (size_t)BB * RR * 4;
  float* feat= (float*)(ws + off); off += (size_t)BB * 200 * 4;

  hipMemsetAsync(feat, 0, BB * 200 * 4, stream);
  prep_w<<<(FP * DD + 255) / 256, 256, 0, stream>>>(Wconv, Whg, Wlg);
  gemm_att<<<dim3(256), 512, 0, stream>>>(lv, rv, llen, rlen, lpart, rpart);
  stats_merge<<<dim3(256), 256, 0, stream>>>(lpart, rpart, llen, rlen,
                                             lwv, lan, lidx, rwv, ran, ridx);
  conv_pool_mfma<<<dim3(512), 256, 0, stream>>>(lv, rv, lwv, lan, lidx,
                                                rwv, ran, ridx, llen, rlen,
                                                Whg, Wlg, bconv, feat);
  dense_out<<<BB, 64, 0, stream>>>(feat, Wd, bd, out);
}

// Round 7
// 121.023 us; speedup vs baseline: 4.1272x; 1.1209x over previous
//
#include <hip/hip_runtime.h>
#include <math.h>

#define BB 64
#define LL 512
#define RR 512
#define DD 512
#define FC 100
#define FP 112
#define HH 60
#define BD (BB*DD)

typedef __attribute__((ext_vector_type(8))) short bf16x8;
typedef __attribute__((ext_vector_type(4))) float f32x4;

__device__ __forceinline__ unsigned short bf16rne(float x) {
  unsigned u = __float_as_uint(x);
  return (unsigned short)((u + 0x7fffu + ((u >> 16) & 1u)) >> 16);
}
__device__ __forceinline__ float bf16tof(unsigned short h) {
  return __uint_as_float((unsigned)h << 16);
}

// Truncating hi/lo bf16 split of 2 floats, packed via v_perm_b32.
__device__ __forceinline__ void split2(float x0, float x1, unsigned& h2, unsigned& l2) {
  unsigned u0 = __float_as_uint(x0), u1 = __float_as_uint(x1);
  h2 = __builtin_amdgcn_perm(u1, u0, 0x07060302u);
  float r0 = x0 - __uint_as_float(u0 & 0xffff0000u);
  float r1 = x1 - __uint_as_float(u1 & 0xffff0000u);
  l2 = __builtin_amdgcn_perm(__float_as_uint(r1), __float_as_uint(r0), 0x07060302u);
}

// DPP row_ror reductions over the 16-lane DPP row (= fr lanes, fixed kh).
// VALU-pipe cross-lane: ~2-4cyc latency vs ~35cyc ds_bpermute, pipelines across rows.
template <int N>
__device__ __forceinline__ float ror_max_f(float v) {
  return fmaxf(v, __uint_as_float(__builtin_amdgcn_mov_dpp(__float_as_uint(v), 0x120 | N, 0xf, 0xf, true)));
}
template <int N>
__device__ __forceinline__ float ror_add_f(float v) {
  return v + __uint_as_float(__builtin_amdgcn_mov_dpp(__float_as_uint(v), 0x120 | N, 0xf, 0xf, true));
}
template <int N>
__device__ __forceinline__ int ror_min_i(int v) {
  int o = __builtin_amdgcn_mov_dpp(v, 0x120 | N, 0xf, 0xf, true);
  return o < v ? o : v;
}
__device__ __forceinline__ float row16_max(float v) {
  v = ror_max_f<1>(v); v = ror_max_f<2>(v); v = ror_max_f<4>(v); return ror_max_f<8>(v);
}
__device__ __forceinline__ float row16_sum(float v) {
  v = ror_add_f<1>(v); v = ror_add_f<2>(v); v = ror_add_f<4>(v); return ror_add_f<8>(v);
}
__device__ __forceinline__ int row16_min(int v) {
  v = ror_min_i<1>(v); v = ror_min_i<2>(v); v = ror_min_i<4>(v); return ror_min_i<8>(v);
}

// ---------------- fused attention GEMM + softmax-stat partials ----------------
// 256x256 tile, bf16 hi/lo 3-pass MFMA; epilogue reduces row-wise (att_l) and
// col-wise (att_r) partials {M, zv, q2, idx}; z0 reconstructed later from
// z0 = zv + n_invalid*exp(-10-M) (invalid logits are exactly -10).
// bS==M identity: max-over-valid == global max (P[violation]~1e-124).
__global__ __launch_bounds__(512, 2) void gemm_att(const float* __restrict__ lv,
                                                   const float* __restrict__ rv,
                                                   const int* __restrict__ llen,
                                                   const int* __restrict__ rlen,
                                                   float4* __restrict__ lpart,
                                                   float4* __restrict__ rpart) {
  __shared__ __align__(16) unsigned short Ah[256][40];
  __shared__ __align__(16) unsigned short Al[256][40];
  __shared__ __align__(16) unsigned short Bh[256][40];
  __shared__ __align__(16) unsigned short Bl[256][40];

  // 256 blocks, 8 XCDs -> 32 contiguous wids per XCD = 8 whole batches per XCD.
  const int bid = blockIdx.x;
  const int wid = (bid & 7) * 32 + (bid >> 3);
  const int b  = wid >> 2;
  const int l0 = ((wid >> 1) & 1) * 256;
  const int r0 = (wid & 1) * 256;

  const int t = threadIdx.x;       // 0..511
  const int srow = t >> 1;         // 0..255
  const int half = t & 1;
  const int kq = half * 16;        // ushort col base in BK=32 chunk

  const float* Abase = lv + (size_t)(l0 + srow) * BD + b * DD + kq;
  const float* Bbase = rv + (size_t)(r0 + srow) * BD + b * DD + kq;

  float4 pa[4], pb[4];
#pragma unroll
  for (int q = 0; q < 4; ++q) {
    pa[q] = *(const float4*)(Abase + q * 4);
    pb[q] = *(const float4*)(Bbase + q * 4);
  }

  const int lane = t & 63;
  const int wv = t >> 6;           // 0..7
  const int wrow = wv >> 2;        // 0..1 -> 128-row l slice
  const int wcol = wv & 3;         // 0..3 -> 64-col r slice
  const int fr = lane & 15;
  const int kh = lane >> 4;        // 0..3

  f32x4 acc[8][4];
#pragma unroll
  for (int i = 0; i < 8; ++i)
#pragma unroll
    for (int j = 0; j < 4; ++j) acc[i][j] = (f32x4){0.f, 0.f, 0.f, 0.f};

  for (int it = 0; it < 16; ++it) {
    __syncthreads();   // previous MFMA reads done
#pragma unroll
    for (int q = 0; q < 4; ++q) {
      unsigned h01, l01, h23, l23;
      split2(pa[q].x, pa[q].y, h01, l01);
      split2(pa[q].z, pa[q].w, h23, l23);
      *(uint2*)&Ah[srow][kq + q * 4] = make_uint2(h01, h23);
      *(uint2*)&Al[srow][kq + q * 4] = make_uint2(l01, l23);
      split2(pb[q].x, pb[q].y, h01, l01);
      split2(pb[q].z, pb[q].w, h23, l23);
      *(uint2*)&Bh[srow][kq + q * 4] = make_uint2(h01, h23);
      *(uint2*)&Bl[srow][kq + q * 4] = make_uint2(l01, l23);
    }
    if (it < 15) {
      const float* An = Abase + (it + 1) * 32;
      const float* Bn = Bbase + (it + 1) * 32;
#pragma unroll
      for (int q = 0; q < 4; ++q) {
        pa[q] = *(const float4*)(An + q * 4);
        pb[q] = *(const float4*)(Bn + q * 4);
      }
    }
    __syncthreads();   // LDS writes visible

    bf16x8 bh[4], bl[4];
#pragma unroll
    for (int j = 0; j < 4; ++j) {
      bh[j] = *(const bf16x8*)&Bh[wcol * 64 + j * 16 + fr][kh * 8];
      bl[j] = *(const bf16x8*)&Bl[wcol * 64 + j * 16 + fr][kh * 8];
    }
#pragma unroll
    for (int i = 0; i < 8; ++i) {
      bf16x8 ah = *(const bf16x8*)&Ah[wrow * 128 + i * 16 + fr][kh * 8];
      bf16x8 al = *(const bf16x8*)&Al[wrow * 128 + i * 16 + fr][kh * 8];
#pragma unroll
      for (int j = 0; j < 4; ++j) {
        acc[i][j] = __builtin_amdgcn_mfma_f32_16x16x32_bf16(ah, bh[j], acc[i][j], 0, 0, 0);
        acc[i][j] = __builtin_amdgcn_mfma_f32_16x16x32_bf16(ah, bl[j], acc[i][j], 0, 0, 0);
        acc[i][j] = __builtin_amdgcn_mfma_f32_16x16x32_bf16(al, bh[j], acc[i][j], 0, 0, 0);
      }
    }
  }

  // ================= fused stats epilogue =================
  const int ll_ = llen[b], rl_ = rlen[b];
  __syncthreads();                       // all waves done with staging LDS
  float4* rowsc = (float4*)&Ah[0][0];    // [4 wcol][256 row]  (16 KB, aliases Ah/Al)
  float4* colsc = (float4*)&Bh[0][0];    // [2 wrow][256 col]  (8 KB, aliases Bh)

  // ---- row-side (att_l: softmax over r). s = !vr ? -10 : (vl ? raw : 0) ----
  const int rbase = r0 + wcol * 64 + fr;
  bool vr4[4]; int rr4[4];
#pragma unroll
  for (int j = 0; j < 4; ++j) { rr4[j] = rbase + j * 16; vr4[j] = rr4[j] < rl_; }

#pragma unroll
  for (int i = 0; i < 8; ++i) {
#pragma unroll
    for (int q = 0; q < 4; ++q) {
      const int trow = wrow * 128 + i * 16 + kh * 4 + q;   // 0..255 in tile
      const bool vl = (l0 + trow) < ll_;
      float s[4];
      float M = -1e30f;
#pragma unroll
      for (int j = 0; j < 4; ++j) {
        float raw = acc[i][j][q];
        s[j] = !vr4[j] ? -10.f : (vl ? raw : 0.f);
        M = fmaxf(M, s[j]);
      }
      M = row16_max(M);
      float zv = 0.f, q2 = 0.f;
      int loc = 0x7fffffff;
#pragma unroll
      for (int j = 0; j < 4; ++j) {
        float e = __expf(s[j] - M);
        if (vr4[j]) {
          zv += e; q2 += e * e;
          if (s[j] == M && rr4[j] < loc) loc = rr4[j];
        }
      }
      zv = row16_sum(zv);
      q2 = row16_sum(q2);
      loc = row16_min(loc);
      if (fr == 0)
        rowsc[wcol * 256 + trow] = make_float4(M, zv, q2, __int_as_float(loc));
    }
  }

  // ---- col-side (att_r: softmax over l). s = !vl ? -10 : (vr ? raw : 0) ----
#pragma unroll
  for (int j = 0; j < 4; ++j) {
    const int tcol = wcol * 64 + j * 16 + fr;              // 0..255 in tile
    const bool vr = (r0 + tcol) < rl_;
    float M = -1e30f;
#pragma unroll
    for (int i = 0; i < 8; ++i)
#pragma unroll
      for (int q = 0; q < 4; ++q) {
        int lg = l0 + wrow * 128 + i * 16 + kh * 4 + q;
        bool vl = lg < ll_;
        float sv = !vl ? -10.f : (vr ? acc[i][j][q] : 0.f);
        M = fmaxf(M, sv);
      }
    M = fmaxf(M, __shfl_xor(M, 16, 64));
    M = fmaxf(M, __shfl_xor(M, 32, 64));
    float zv = 0.f, q2 = 0.f;
    int loc = 0x7fffffff;
#pragma unroll
    for (int i = 0; i < 8; ++i)
#pragma unroll
      for (int q = 0; q < 4; ++q) {
        int lg = l0 + wrow * 128 + i * 16 + kh * 4 + q;
        bool vl = lg < ll_;
        float sv = !vl ? -10.f : (vr ? acc[i][j][q] : 0.f);
        float e = __expf(sv - M);
        if (vl) {
          zv += e; q2 += e * e;
          if (sv == M && lg < loc) loc = lg;
        }
      }
    zv += __shfl_xor(zv, 16, 64); zv += __shfl_xor(zv, 32, 64);
    q2 += __shfl_xor(q2, 16, 64); q2 += __shfl_xor(q2, 32, 64);
    { int o = __shfl_xor(loc, 16, 64); loc = o < loc ? o : loc; }
    { int o = __shfl_xor(loc, 32, 64); loc = o < loc ? o : loc; }
    if (kh == 0)
      colsc[wrow * 256 + tcol] = make_float4(M, zv, q2, __int_as_float(loc));
  }

  __syncthreads();

  // ---- block merge + partial write ----
  if (t < 256) {
    float4 p = rowsc[t];
    float M = p.x, zv = p.y, q2 = p.z;
    int loc = __float_as_int(p.w);
#pragma unroll
    for (int w2 = 1; w2 < 4; ++w2) {                      // ascending r slices
      float4 o = rowsc[w2 * 256 + t];
      float M1 = o.x;
      float Mn = fmaxf(M, M1);
      float c0 = __expf(M - Mn), c1 = __expf(M1 - Mn);
      zv = zv * c0 + o.y * c1;
      q2 = q2 * c0 * c0 + o.z * c1 * c1;
      int loc1 = __float_as_int(o.w);
      loc = (M1 > M) ? loc1 : ((M1 == M && loc1 < loc) ? loc1 : loc);
      M = Mn;
    }
    lpart[((size_t)(b * 512 + l0 + t)) * 2 + (r0 >> 8)] =
        make_float4(M, zv, q2, __int_as_float(loc));
  } else {
    const int c = t - 256;
    float4 p = colsc[c];
    float M = p.x, zv = p.y, q2 = p.z;
    int loc = __float_as_int(p.w);
    {
      float4 o = colsc[256 + c];                          // wrow 1 = higher l
      float M1 = o.x;
      float Mn = fmaxf(M, M1);
      float c0 = __expf(M - Mn), c1 = __expf(M1 - Mn);
      zv = zv * c0 + o.y * c1;
      q2 = q2 * c0 * c0 + o.z * c1 * c1;
      int loc1 = __float_as_int(o.w);
      loc = (M1 > M) ? loc1 : ((M1 == M && loc1 < loc) ? loc1 : loc);
      M = Mn;
    }
    rpart[((size_t)(b * 512 + r0 + c)) * 2 + (l0 >> 8)] =
        make_float4(M, zv, q2, __int_as_float(loc));
  }
}

// ---------------- merge 2 slice-partials per row/col -> final stats ----------------
__global__ __launch_bounds__(256) void stats_merge(const float4* __restrict__ lpart,
    const float4* __restrict__ rpart,
    const int* __restrict__ llen, const int* __restrict__ rlen,
    float* __restrict__ lwv, float* __restrict__ lan, int* __restrict__ lidx,
    float* __restrict__ rwv, float* __restrict__ ran, int* __restrict__ ridx) {
  const int gid = blockIdx.x * 256 + threadIdx.x;  // 0..65535
  const int side = gid >> 15;
  const int pos = gid & 32767;                     // b*512 + p
  const int b = pos >> 9, p = pos & 511;
  const float4* part = (side ? rpart : lpart) + (size_t)pos * 2;
  float4 P0 = part[0], P1 = part[1];
  float M = P0.x, zv = P0.y, q2 = P0.z;
  int loc = __float_as_int(P0.w);
  {
    float M1 = P1.x;
    float Mn = fmaxf(M, M1);
    float c0 = __expf(M - Mn), c1 = __expf(M1 - Mn);
    zv = zv * c0 + P1.y * c1;
    q2 = q2 * c0 * c0 + P1.z * c1 * c1;
    int loc1 = __float_as_int(P1.w);
    loc = (M1 > M) ? loc1 : ((M1 == M && loc1 < loc) ? loc1 : loc);
    M = Mn;
  }
  const int len = side ? llen[b] : rlen[b];   // att_l sums /rl ; att_r sums /ll
  const int own = side ? rlen[b] : llen[b];
  const int ninv = side ? (LL - llen[b]) : (RR - rlen[b]);
  float z0 = zv + (float)ninv * __expf(-10.f - M);
  float S = zv / z0;
  float inv = 1.f / (S + 1e-13f);
  float sumq = S * inv;
  float mean = sumq / (float)len;
  float sumq2 = q2 / (z0 * z0) * inv * inv;
  float var = sumq2 / (float)len - mean * mean;
  float wv = var / fmaxf(mean, 0.001f);
  float qmax = inv / z0;                      // exp(M-M)/z0 * inv
  float an = qmax / fmaxf(qmax, 0.001f);
  int idx = (p < own && loc != 0x7fffffff) ? loc : 0;
  if (side == 0) { lwv[pos] = wv; lan[pos] = an; lidx[pos] = idx; }
  else           { rwv[pos] = wv; ran[pos] = an; ridx[pos] = idx; }
}

// ---------------- prep: Wconv [100][512] -> bf16 hi/lo [112][512] (f-major, zero-padded) ------
__global__ void prep_w(const float* __restrict__ Wconv,
                       unsigned short* __restrict__ Whg, unsigned short* __restrict__ Wlg) {
  int i = blockIdx.x * 256 + threadIdx.x;
  if (i < FP * DD) {
    int f = i >> 9;
    float w = (f < FC) ? Wconv[i] : 0.f;
    unsigned short h = bf16rne(w);
    unsigned short l = bf16rne(w - bf16tof(h));
    Whg[i] = h; Wlg[i] = l;
  }
}

// ---------------- conv + relu + masked maxpool via bf16 hi/lo MFMA ----------------
__global__ __launch_bounds__(256) void conv_pool_mfma(const float* __restrict__ lv,
    const float* __restrict__ rv,
    const float* __restrict__ lwv, const float* __restrict__ lan, const int* __restrict__ lidx,
    const float* __restrict__ rwv, const float* __restrict__ ran, const int* __restrict__ ridx,
    const int* __restrict__ llen, const int* __restrict__ rlen,
    const unsigned short* __restrict__ Whg, const unsigned short* __restrict__ Wlg,
    const float* __restrict__ bconv, float* __restrict__ feat) {
  __shared__ __align__(16) unsigned short Ah[128][40];
  __shared__ __align__(16) unsigned short Al[128][40];
  __shared__ __align__(16) unsigned short Wh[FP][40];
  __shared__ __align__(16) unsigned short Wl[FP][40];
  __shared__ float pool[4][FP];
  __shared__ float ppw[128], ppa[128];
  __shared__ int   ppi[128], ppv[128];

  const int bid = blockIdx.x;
  const int wid = (bid & 7) * 64 + (bid >> 3);
  const int side = wid >> 8;
  const int b    = (wid >> 2) & 63;
  const int s0   = (wid & 3) * 128;

  const int t = threadIdx.x;
  const float* x; const float* y; const float* wb; const float* ab; const int* ib; int plen;
  if (side == 0) { x = lv; y = rv; wb = lwv; ab = lan; ib = lidx; plen = llen[b]; }
  else           { x = rv; y = lv; wb = rwv; ab = ran; ib = ridx; plen = rlen[b]; }

  if (t < 128) {
    int pos = s0 + t;
    ppw[t] = wb[b * 512 + pos];
    ppa[t] = ab[b * 512 + pos];
    ppi[t] = ib[b * 512 + pos];
    ppv[t] = (pos < plen) ? 1 : 0;
  }
  __syncthreads();

  const int pos  = t >> 1;
  const int half = t & 1;
  const float w_ = ppw[pos];
  const float a_ = ppa[pos];
  const int   yi = ppi[pos];
  const float* xp = x + (size_t)(s0 + pos) * BD + b * DD + half * 16;
  const float* yp = y + (size_t)yi * BD + b * DD + half * 16;

  float4 xv[4], yv[4];
#pragma unroll
  for (int q = 0; q < 4; ++q) {
    xv[q] = *(const float4*)(xp + q * 4);
    yv[q] = *(const float4*)(yp + q * 4);
  }

  const int lane = t & 63;
  const int wvi = t >> 6;        // wave 0..3
  const int m0 = wvi * 32;
  const int fr = lane & 15;
  const int kh = lane >> 4;

  f32x4 acc[2][7];
#pragma unroll
  for (int i = 0; i < 2; ++i)
#pragma unroll
    for (int j = 0; j < 7; ++j) acc[i][j] = (f32x4){0.f, 0.f, 0.f, 0.f};

  for (int it = 0; it < 16; ++it) {
    const int k0 = it * 32;
    __syncthreads();
#pragma unroll
    for (int q = 0; q < 2; ++q) {
      float d0 = w_ * fabsf(xv[2*q].x   - a_ * yv[2*q].x);
      float d1 = w_ * fabsf(xv[2*q].y   - a_ * yv[2*q].y);
      float d2 = w_ * fabsf(xv[2*q].z   - a_ * yv[2*q].z);
      float d3 = w_ * fabsf(xv[2*q].w   - a_ * yv[2*q].w);
      float d4 = w_ * fabsf(xv[2*q+1].x - a_ * yv[2*q+1].x);
      float d5 = w_ * fabsf(xv[2*q+1].y - a_ * yv[2*q+1].y);
      float d6 = w_ * fabsf(xv[2*q+1].z - a_ * yv[2*q+1].z);
      float d7 = w_ * fabsf(xv[2*q+1].w - a_ * yv[2*q+1].w);
      unsigned h01, l01, h23, l23, h45, l45, h67, l67;
      split2(d0, d1, h01, l01);
      split2(d2, d3, h23, l23);
      split2(d4, d5, h45, l45);
      split2(d6, d7, h67, l67);
      *(uint4*)&Ah[pos][half * 16 + q * 8] = make_uint4(h01, h23, h45, h67);
      *(uint4*)&Al[pos][half * 16 + q * 8] = make_uint4(l01, l23, l45, l67);
    }
#pragma unroll
    for (int rep = 0; rep < 2; ++rep) {
      int idx = t + rep * 256;
      if (idx < FP * 4) {
        int f = idx >> 2, q = idx & 3;
        *(ulonglong2*)&Wh[f][q * 8] = *(const ulonglong2*)&Whg[f * DD + k0 + q * 8];
        *(ulonglong2*)&Wl[f][q * 8] = *(const ulonglong2*)&Wlg[f * DD + k0 + q * 8];
      }
    }
    if (it < 15) {
      const float* xn = xp + k0 + 32;
      const float* yn = yp + k0 + 32;
#pragma unroll
      for (int q = 0; q < 4; ++q) {
        xv[q] = *(const float4*)(xn + q * 4);
        yv[q] = *(const float4*)(yn + q * 4);
      }
    }
    __syncthreads();

    bf16x8 ah[2], al[2];
#pragma unroll
    for (int i = 0; i < 2; ++i) {
      ah[i] = *(const bf16x8*)&Ah[m0 + i * 16 + fr][kh * 8];
      al[i] = *(const bf16x8*)&Al[m0 + i * 16 + fr][kh * 8];
    }
#pragma unroll
    for (int j = 0; j < 7; ++j) {
      bf16x8 bh = *(const bf16x8*)&Wh[j * 16 + fr][kh * 8];
      bf16x8 bl = *(const bf16x8*)&Wl[j * 16 + fr][kh * 8];
#pragma unroll
      for (int i = 0; i < 2; ++i) {
        acc[i][j] = __builtin_amdgcn_mfma_f32_16x16x32_bf16(ah[i], bh, acc[i][j], 0, 0, 0);
        acc[i][j] = __builtin_amdgcn_mfma_f32_16x16x32_bf16(ah[i], bl, acc[i][j], 0, 0, 0);
        acc[i][j] = __builtin_amdgcn_mfma_f32_16x16x32_bf16(al[i], bh, acc[i][j], 0, 0, 0);
      }
    }
  }

  // epilogue: bias + relu + validity + maxpool
#pragma unroll
  for (int j = 0; j < 7; ++j) {
    int f = j * 16 + fr;
    float bcv = (f < FC) ? bconv[f] : 0.f;
    float vmax = -1e30f;
#pragma unroll
    for (int i = 0; i < 2; ++i) {
#pragma unroll
      for (int q = 0; q < 4; ++q) {
        int sl = m0 + i * 16 + kh * 4 + q;
        if (ppv[sl]) vmax = fmaxf(vmax, fmaxf(acc[i][j][q] + bcv, 0.f));
      }
    }
    vmax = fmaxf(vmax, __shfl_xor(vmax, 16, 64));
    vmax = fmaxf(vmax, __shfl_xor(vmax, 32, 64));
    if (lane < 16) pool[wvi][f] = vmax;
  }
  __syncthreads();
  if (t < FC) {
    float v = fmaxf(fmaxf(pool[0][t], pool[1][t]), fmaxf(pool[2][t], pool[3][t]));
    if (v > -1e29f) atomicMax((int*)&feat[b * 200 + side * FC + t], __float_as_int(v));
  }
}

// ---------------- final dense [B,200] x [200,60] + relu ----------------
__global__ void dense_out(const float* __restrict__ feat, const float* __restrict__ Wd,
                          const float* __restrict__ bd, float* __restrict__ out) {
  int b = blockIdx.x, h = threadIdx.x;
  if (h < HH) {
    float s = bd[h];
    const float* fb = feat + b * 200;
    const float* wr = Wd + h * 200;
    for (int k = 0; k < 200; ++k) s += fb[k] * wr[k];
    out[b * HH + h] = fmaxf(s, 0.f);
  }
}

extern "C" void kernel_launch(void* const* d_in, const int* in_sizes, int n_in,
                              void* d_out, int out_size, void* d_ws, size_t ws_size,
                              hipStream_t stream) {
  (void)in_sizes; (void)n_in; (void)out_size; (void)ws_size;
  const int*   llen  = (const int*)d_in[0];
  const float* lv    = (const float*)d_in[1];
  const int*   rlen  = (const int*)d_in[2];
  const float* rv    = (const float*)d_in[3];
  const float* Wconv = (const float*)d_in[4];
  const float* bconv = (const float*)d_in[5];
  const float* Wd    = (const float*)d_in[6];
  const float* bd    = (const float*)d_in[7];
  float* out = (float*)d_out;
  char* ws = (char*)d_ws;
  size_t off = 0;
  unsigned short* Whg = (unsigned short*)(ws + off); off += (size_t)FP * DD * 2;
  unsigned short* Wlg = (unsigned short*)(ws + off); off += (size_t)FP * DD * 2;
  float4* lpart = (float4*)(ws + off); off += (size_t)BB * LL * 2 * 16;   // 1 MiB
  float4* rpart = (float4*)(ws + off); off += (size_t)BB * RR * 2 * 16;   // 1 MiB
  float* lwv = (float*)(ws + off); off += (size_t)BB * LL * 4;
  float* lan = (float*)(ws + off); off += (size_t)BB * LL * 4;
  int*   lidx= (int*)  (ws + off); off += (size_t)BB * LL * 4;
  float* rwv = (float*)(ws + off); off += (size_t)BB * RR * 4;
  float* ran = (float*)(ws + off); off += (size_t)BB * RR * 4;
  int*   ridx= (int*)  (ws + off); off += (size_t)BB * RR * 4;
  float* feat= (float*)(ws + off); off += (size_t)BB * 200 * 4;

  hipMemsetAsync(feat, 0, BB * 200 * 4, stream);
  prep_w<<<(FP * DD + 255) / 256, 256, 0, stream>>>(Wconv, Whg, Wlg);
  gemm_att<<<dim3(256), 512, 0, stream>>>(lv, rv, llen, rlen, lpart, rpart);
  stats_merge<<<dim3(256), 256, 0, stream>>>(lpart, rpart, llen, rlen,
                                             lwv, lan, lidx, rwv, ran, ridx);
  conv_pool_mfma<<<dim3(512), 256, 0, stream>>>(lv, rv, lwv, lan, lidx,
                                                rwv, ran, ridx, llen, rlen,
                                                Whg, Wlg, bconv, feat);
  dense_out<<<BB, 64, 0, stream>>>(feat, Wd, bd, out);
}